// Round 3
// baseline (202.299 us; speedup 1.0000x reference)
//
#include <hip/hip_runtime.h>
#include <cstdint>
#include <cstddef>

// Problem: B=32, S=2048, D=512, H=512
//   sb[b,h]   = state @ W1[:D]                  (fp32, tiny)
//   h         = tanh(tanh(sb + input@W1[D:]))   <-- DOUBLE tanh (reference quirk)
//   logit[b,s]= sum_h h * w2[h]  - 1e30*(1-mask)
//   p = softmax over S;  pooled[b,d] = sum_s p*input
// Outputs: pooled (16384 f32) ++ logit (65536 f32)

#define NEG_BIG 1e30f

typedef __attribute__((ext_vector_type(8))) short short8_t;   // 8 x bf16
typedef __attribute__((ext_vector_type(4))) float f32x4;

__device__ inline unsigned short f2bf(float f){
  union { float f; unsigned int u; } v; v.f = f;
  unsigned int r = v.u + 0x7fffu + ((v.u >> 16) & 1u);   // RNE
  return (unsigned short)(r >> 16);
}
__device__ inline float bf2f(unsigned int lo16){
  union { unsigned int u; float f; } v; v.u = lo16 << 16; return v.f;
}
__device__ inline float tanh_fast(float x){
  x = fminf(fmaxf(x, -15.0f), 15.0f);
  float e = __expf(2.0f * x);
  return (e - 1.0f) / (e + 1.0f);
}

typedef __attribute__((address_space(1))) const unsigned int g_u32;
typedef __attribute__((address_space(3))) unsigned int l_u32;
__device__ inline void gload16(const unsigned short* g, unsigned short* l){
  // async global->LDS, 16B/lane; LDS dest = uniform base + lane*16 (HW rule)
  __builtin_amdgcn_global_load_lds((g_u32*)g, (l_u32*)l, 16, 0, 0);
}

// ---------------------------------------------------------------- K0b: input -> bf16 copy
__global__ __launch_bounds__(256) void k0b_cvt(const float* __restrict__ in,
                                               unsigned short* __restrict__ inb){
  const int tid = blockIdx.x*256 + threadIdx.x;       // 524288 threads
  const float4* in4 = (const float4*)in;
  ushort4* o4 = (ushort4*)inb;
  #pragma unroll
  for (int it = 0; it < 16; ++it){
    const size_t i = (size_t)it*524288 + tid;         // 8388608 float4 total
    const float4 v = in4[i];
    ushort4 o; o.x=f2bf(v.x); o.y=f2bf(v.y); o.z=f2bf(v.z); o.w=f2bf(v.w);
    o4[i] = o;
  }
}

// ---------------------------------------------------------------- K0: prep
// blocks 0..31  : sb[b,h] = state[b,:] @ W1[:512,h]
// blocks 32..95 : w1xt[h][k] = bf16(W1[512+k][h])
__global__ __launch_bounds__(256) void k0_prep(const float* __restrict__ state,
                                               const float* __restrict__ W1,
                                               float* __restrict__ sb,
                                               unsigned short* __restrict__ w1xt){
  const int bid = blockIdx.x, t = threadIdx.x;
  if (bid < 32) {
    __shared__ float st[512];
    st[t]       = state[bid*512 + t];
    st[t + 256] = state[bid*512 + t + 256];
    __syncthreads();
    for (int hh = t; hh < 512; hh += 256){
      float acc = 0.f;
      #pragma unroll 4
      for (int d = 0; d < 512; ++d) acc += st[d] * W1[(size_t)d*512 + hh];
      sb[bid*512 + hh] = acc;
    }
  } else {
    const int q  = bid - 32;
    const int k0 = (q >> 3) * 64, h0 = (q & 7) * 64;
    __shared__ float tile[64][65];
    const int c = t & 63, r0 = t >> 6;
    #pragma unroll
    for (int i = 0; i < 16; ++i){
      int r = r0 + 4*i;
      tile[r][c] = W1[(size_t)(512 + k0 + r)*512 + h0 + c];
    }
    __syncthreads();
    #pragma unroll
    for (int i = 0; i < 16; ++i){
      int r = r0 + 4*i;
      w1xt[(size_t)(h0 + r)*512 + k0 + c] = f2bf(tile[c][r]);
    }
  }
}

// ---------------------------------------------------------------- K1 fast: gload_lds GEMM
// LDS layout: linear [128 rows][8 chunks of 16B]; physical chunk = logical ^ (row&7).
// Staged with linear LDS dest + inverse-swizzled per-lane GLOBAL source (rule #21).
__global__ __launch_bounds__(256) void k1_gemm_fast(const unsigned short* __restrict__ inb,
                                                    const unsigned short* __restrict__ w1xt,
                                                    const float* __restrict__ sb,
                                                    const float* __restrict__ w2,
                                                    float* __restrict__ plog){
  __shared__ unsigned short lds_a[128*64];
  __shared__ unsigned short lds_b[128*64];

  const int orig = blockIdx.x;                 // XCD-grouped swizzle
  const int xcd  = orig & 7, slot = orig >> 3;
  const int mtile = xcd*64 + (slot >> 2);
  const int nt    = slot & 3;
  const int m0 = mtile * 128, n0 = nt * 128;
  const int b  = m0 >> 11;

  const int t = threadIdx.x;
  const int lane = t & 63, wid = t >> 6;
  const int wr = wid >> 1, wc = wid & 1;
  const int lr = lane & 15, kg = lane >> 4;
  const int l7 = lr & 7;

  // staging source (per-lane pre-swizzled global addr)
  const int srow = wid*32 + (lane >> 3);                    // 0..127
  const int scol = ((lane & 7) ^ ((lane >> 3) & 7)) * 8;    // logical chunk for this slot
  const unsigned short* gA = inb  + (size_t)(m0 + srow)*512 + scol;
  const unsigned short* gB = w1xt + (size_t)(n0 + srow)*512 + scol;
  unsigned short* lA = &lds_a[(wid*4)*512];
  unsigned short* lB = &lds_b[(wid*4)*512];

  // fragment read bases (physical chunk = logical ^ l7); mi/ni via imm offsets
  const unsigned short* rA0 = &lds_a[(wr*64 + lr)*64 + ((kg    ) ^ l7)*8]; // ks=0
  const unsigned short* rA1 = &lds_a[(wr*64 + lr)*64 + ((4 + kg) ^ l7)*8]; // ks=32
  const unsigned short* rB0 = &lds_b[(wc*64 + lr)*64 + ((kg    ) ^ l7)*8];
  const unsigned short* rB1 = &lds_b[(wc*64 + lr)*64 + ((4 + kg) ^ l7)*8];

  f32x4 acc[4][4];
  #pragma unroll
  for (int mi = 0; mi < 4; ++mi)
    #pragma unroll
    for (int ni = 0; ni < 4; ++ni) acc[mi][ni] = (f32x4){0.f,0.f,0.f,0.f};

  for (int kk = 0; kk < 512; kk += 64){
    #pragma unroll
    for (int i = 0; i < 4; ++i) gload16(gA + kk + i*8*512, lA + i*512);
    #pragma unroll
    for (int i = 0; i < 4; ++i) gload16(gB + kk + i*8*512, lB + i*512);
    __syncthreads();   // compiler drains vmcnt before barrier

    short8_t af[4], bfr[4];
    #pragma unroll
    for (int mi = 0; mi < 4; ++mi) af[mi]  = *(const short8_t*)(rA0 + mi*1024);
    #pragma unroll
    for (int ni = 0; ni < 4; ++ni) bfr[ni] = *(const short8_t*)(rB0 + ni*1024);
    #pragma unroll
    for (int mi = 0; mi < 4; ++mi)
      #pragma unroll
      for (int ni = 0; ni < 4; ++ni)
        acc[mi][ni] = __builtin_amdgcn_mfma_f32_16x16x32_bf16(af[mi], bfr[ni], acc[mi][ni], 0, 0, 0);
    #pragma unroll
    for (int mi = 0; mi < 4; ++mi) af[mi]  = *(const short8_t*)(rA1 + mi*1024);
    #pragma unroll
    for (int ni = 0; ni < 4; ++ni) bfr[ni] = *(const short8_t*)(rB1 + ni*1024);
    #pragma unroll
    for (int mi = 0; mi < 4; ++mi)
      #pragma unroll
      for (int ni = 0; ni < 4; ++ni)
        acc[mi][ni] = __builtin_amdgcn_mfma_f32_16x16x32_bf16(af[mi], bfr[ni], acc[mi][ni], 0, 0, 0);
    __syncthreads();
  }

  // epilogue: tanh(tanh(acc + sb)) * w2, reduce over 128 h-cols of this block
  float w2v[4], sbv[4];
  #pragma unroll
  for (int ni = 0; ni < 4; ++ni){
    const int h = n0 + wc*64 + ni*16 + lr;
    w2v[ni] = w2[h];
    sbv[ni] = sb[b*512 + h];
  }
  float* red = reinterpret_cast<float*>(&lds_a[0]);
  #pragma unroll
  for (int mi = 0; mi < 4; ++mi){
    #pragma unroll
    for (int j = 0; j < 4; ++j){
      float v = 0.f;
      #pragma unroll
      for (int ni = 0; ni < 4; ++ni)
        v += tanh_fast(tanh_fast(acc[mi][ni][j] + sbv[ni])) * w2v[ni];
      v += __shfl_xor(v, 1); v += __shfl_xor(v, 2);
      v += __shfl_xor(v, 4); v += __shfl_xor(v, 8);
      if (lr == 0){
        const int rloc = wr*64 + mi*16 + kg*4 + j;    // C/D row=(lane>>4)*4+j
        red[wc*128 + rloc] = v;
      }
    }
  }
  __syncthreads();
  if (t < 128) plog[(size_t)nt*65536 + m0 + t] = red[t] + red[128 + t];
}

// ---------------------------------------------------------------- K1 fallback (reg-staged, pad-72)
__global__ __launch_bounds__(256) void k1_gemm_fb(const float* __restrict__ input,
                                                  const unsigned short* __restrict__ w1xt,
                                                  const float* __restrict__ sb,
                                                  const float* __restrict__ w2,
                                                  float* __restrict__ plog){
  __shared__ unsigned short lds_a[128][72];
  __shared__ unsigned short lds_b[128][72];
  const int orig = blockIdx.x;
  const int xcd  = orig & 7, slot = orig >> 3;
  const int mtile = xcd*64 + (slot >> 2);
  const int nt    = slot & 3;
  const int m0 = mtile * 128, n0 = nt * 128;
  const int b  = m0 >> 11;
  const int t = threadIdx.x;
  const int lane = t & 63, wid = t >> 6;
  const int wr = wid >> 1, wc = wid & 1;
  const int lr = lane & 15, kg = lane >> 4;
  f32x4 acc[4][4];
  #pragma unroll
  for (int mi = 0; mi < 4; ++mi)
    #pragma unroll
    for (int ni = 0; ni < 4; ++ni) acc[mi][ni] = (f32x4){0.f,0.f,0.f,0.f};
  const int ar0 = t >> 4, afo = t & 15;
  const int br0 = t >> 3, bho = t & 7;
  for (int kk = 0; kk < 512; kk += 64){
    #pragma unroll
    for (int rr = 0; rr < 8; ++rr){
      const int r = ar0 + rr*16;
      const float4 v = *reinterpret_cast<const float4*>(input + (size_t)(m0 + r)*512 + kk + afo*4);
      ushort4 bv; bv.x=f2bf(v.x); bv.y=f2bf(v.y); bv.z=f2bf(v.z); bv.w=f2bf(v.w);
      *reinterpret_cast<ushort4*>(&lds_a[r][afo*4]) = bv;
    }
    #pragma unroll
    for (int rr = 0; rr < 4; ++rr){
      const int r = br0 + rr*32;
      const uint4 v = *reinterpret_cast<const uint4*>(w1xt + (size_t)(n0 + r)*512 + kk + bho*8);
      *reinterpret_cast<uint4*>(&lds_b[r][bho*8]) = v;
    }
    __syncthreads();
    #pragma unroll
    for (int ks = 0; ks < 64; ks += 32){
      short8_t af[4], bfr[4];
      #pragma unroll
      for (int mi = 0; mi < 4; ++mi)
        af[mi] = *reinterpret_cast<const short8_t*>(&lds_a[wr*64 + mi*16 + lr][ks + kg*8]);
      #pragma unroll
      for (int ni = 0; ni < 4; ++ni)
        bfr[ni] = *reinterpret_cast<const short8_t*>(&lds_b[wc*64 + ni*16 + lr][ks + kg*8]);
      #pragma unroll
      for (int mi = 0; mi < 4; ++mi)
        #pragma unroll
        for (int ni = 0; ni < 4; ++ni)
          acc[mi][ni] = __builtin_amdgcn_mfma_f32_16x16x32_bf16(af[mi], bfr[ni], acc[mi][ni], 0, 0, 0);
    }
    __syncthreads();
  }
  float w2v[4], sbv[4];
  #pragma unroll
  for (int ni = 0; ni < 4; ++ni){
    const int h = n0 + wc*64 + ni*16 + lr;
    w2v[ni] = w2[h]; sbv[ni] = sb[b*512 + h];
  }
  float* red = reinterpret_cast<float*>(&lds_a[0][0]);
  #pragma unroll
  for (int mi = 0; mi < 4; ++mi){
    #pragma unroll
    for (int j = 0; j < 4; ++j){
      float v = 0.f;
      #pragma unroll
      for (int ni = 0; ni < 4; ++ni)
        v += tanh_fast(tanh_fast(acc[mi][ni][j] + sbv[ni])) * w2v[ni];
      v += __shfl_xor(v, 1); v += __shfl_xor(v, 2);
      v += __shfl_xor(v, 4); v += __shfl_xor(v, 8);
      if (lr == 0){
        const int rloc = wr*64 + mi*16 + kg*4 + j;
        red[wc*128 + rloc] = v;
      }
    }
  }
  __syncthreads();
  if (t < 128) plog[(size_t)nt*65536 + m0 + t] = red[t] + red[128 + t];
}

// ---------------------------------------------------------------- K2: softmax stats
__global__ __launch_bounds__(256) void k2_softmax(const float* __restrict__ plog,
                                                  const float* __restrict__ mask,
                                                  float* __restrict__ out_logit,
                                                  float* __restrict__ mz){
  const int b = blockIdx.x, t = threadIdx.x;
  float l[8]; float mx = -3.4e38f;
  #pragma unroll
  for (int i = 0; i < 8; ++i){
    const size_t idx = (size_t)b*2048 + t + i*256;
    float v = plog[idx] + plog[65536 + idx] + plog[2*65536 + idx] + plog[3*65536 + idx];
    v -= NEG_BIG * (1.0f - mask[idx]);
    l[i] = v;
    out_logit[idx] = v;
    mx = fmaxf(mx, v);
  }
  __shared__ float red[8];
  const int wid = t >> 6, lane = t & 63;
  #pragma unroll
  for (int off = 1; off < 64; off <<= 1) mx = fmaxf(mx, __shfl_xor(mx, off));
  if (lane == 0) red[wid] = mx;
  __syncthreads();
  mx = fmaxf(fmaxf(red[0], red[1]), fmaxf(red[2], red[3]));
  float zs = 0.f;
  #pragma unroll
  for (int i = 0; i < 8; ++i) zs += __expf(l[i] - mx);
  #pragma unroll
  for (int off = 1; off < 64; off <<= 1) zs += __shfl_xor(zs, off);
  if (lane == 0) red[4 + wid] = zs;
  __syncthreads();
  if (t == 0){ mz[b*2] = mx; mz[b*2+1] = red[4]+red[5]+red[6]+red[7]; }
}

// ---------------------------------------------------------------- K3 fast: pool from bf16
// grid 512 = (b, sc); t>>7 = row parity half, t&127 -> 4 cols
__global__ __launch_bounds__(256) void k3_pool_bf(const unsigned short* __restrict__ inb,
                                                  const float* __restrict__ logit,
                                                  const float* __restrict__ mz,
                                                  float* __restrict__ pool){
  const int b = blockIdx.x >> 4, sc = blockIdx.x & 15;
  const int t = threadIdx.x;
  __shared__ float p[128];
  const float m = mz[b*2], invZ = 1.0f / mz[b*2+1];
  if (t < 128) p[t] = __expf(logit[(size_t)b*2048 + sc*128 + t] - m) * invZ;
  __syncthreads();
  const int half = t >> 7, cw = t & 127;
  float a0=0.f,a1=0.f,a2=0.f,a3=0.f;
  const unsigned short* base = inb + ((size_t)b*2048 + sc*128 + half)*512 + cw*4;
  #pragma unroll 4
  for (int i = 0; i < 64; ++i){
    const ushort4 v = *reinterpret_cast<const ushort4*>(base + (size_t)i*1024);
    const float pv = p[half + 2*i];
    a0 += pv*bf2f(v.x); a1 += pv*bf2f(v.y); a2 += pv*bf2f(v.z); a3 += pv*bf2f(v.w);
  }
  float4 o = {a0,a1,a2,a3};
  *reinterpret_cast<float4*>(pool + (size_t)blockIdx.x*1024 + half*512 + cw*4) = o;
}

// ---------------------------------------------------------------- K3 fallback: fp32 input
__global__ __launch_bounds__(256) void k3_pool_f32(const float* __restrict__ input,
                                                   const float* __restrict__ logit,
                                                   const float* __restrict__ mz,
                                                   float* __restrict__ pool){
  const int b = blockIdx.x >> 4, sc = blockIdx.x & 15;
  const int t = threadIdx.x;
  __shared__ float p[128];
  const float m = mz[b*2], invZ = 1.0f / mz[b*2+1];
  if (t < 128) p[t] = __expf(logit[(size_t)b*2048 + sc*128 + t] - m) * invZ;
  __syncthreads();
  float a0 = 0.f, a1 = 0.f;
  const float* base = input + ((size_t)b*2048 + sc*128)*512 + 2*t;
  #pragma unroll 4
  for (int i = 0; i < 128; ++i){
    const float2 v = *reinterpret_cast<const float2*>(base + (size_t)i*512);
    a0 += p[i]*v.x; a1 += p[i]*v.y;
  }
  pool[(size_t)blockIdx.x*512 + 2*t]     = a0;
  pool[(size_t)blockIdx.x*512 + 2*t + 1] = a1;
}

// ---------------------------------------------------------------- K4: reduce partials
__global__ __launch_bounds__(256) void k4_reduce(const float* __restrict__ pool,
                                                 float* __restrict__ out_pooled,
                                                 int nchunks){
  const int tg = blockIdx.x*256 + threadIdx.x;  // 0..16383
  const int b = tg >> 9, d = tg & 511;
  float s = 0.f;
  for (int c = 0; c < nchunks; ++c) s += pool[((size_t)b*nchunks + c)*512 + d];
  out_pooled[tg] = s;
}

// ---------------------------------------------------------------- launch
extern "C" void kernel_launch(void* const* d_in, const int* in_sizes, int n_in,
                              void* d_out, int out_size, void* d_ws, size_t ws_size,
                              hipStream_t stream){
  const float* input = (const float*)d_in[0];
  const float* state = (const float*)d_in[1];
  const float* mask  = (const float*)d_in[2];
  const float* W1    = (const float*)d_in[3];
  const float* w2    = (const float*)d_in[4];

  float* out_pooled = (float*)d_out;
  float* out_logit  = (float*)d_out + 16384;

  char* ws = (char*)d_ws;
  const size_t NEED_FAST = 67108864ull + 65536 + 524288 + 1048576 + 256 + 2097152;

  if (ws_size >= NEED_FAST){
    unsigned short* inb  = (unsigned short*)(ws);                          // 64 MB
    float*          sb   = (float*)(ws + 67108864);                        // 64 KB
    unsigned short* w1xt = (unsigned short*)(ws + 67108864 + 65536);       // 512 KB
    float*          plog = (float*)(ws + 67108864 + 589824);               // 1 MB
    float*          mz   = (float*)(ws + 67108864 + 1638400);              // 256 B
    float*          pool = (float*)(ws + 67108864 + 1638656);              // 2 MB

    k0b_cvt     <<<2048, 256, 0, stream>>>(input, inb);
    k0_prep     <<<96,   256, 0, stream>>>(state, W1, sb, w1xt);
    k1_gemm_fast<<<2048, 256, 0, stream>>>(inb, w1xt, sb, w2, plog);
    k2_softmax  <<<32,   256, 0, stream>>>(plog, mask, out_logit, mz);
    k3_pool_bf  <<<512,  256, 0, stream>>>(inb, out_logit, mz, pool);
    k4_reduce   <<<64,   256, 0, stream>>>(pool, out_pooled, 32);
  } else {
    float*          sb   = (float*)(ws);
    unsigned short* w1xt = (unsigned short*)(ws + 65536);
    float*          plog = (float*)(ws + 65536 + 524288);
    float*          mz   = (float*)(ws + 65536 + 524288 + 1048576);
    float*          pool = (float*)(ws + 65536 + 524288 + 1048576 + 256);

    k0_prep   <<<96,   256, 0, stream>>>(state, W1, sb, w1xt);
    k1_gemm_fb<<<2048, 256, 0, stream>>>(input, w1xt, sb, w2, plog);
    k2_softmax<<<32,   256, 0, stream>>>(plog, mask, out_logit, mz);
    k3_pool_f32<<<512, 256, 0, stream>>>(input, out_logit, mz, pool);
    k4_reduce <<<64,   256, 0, stream>>>(pool, out_pooled, 16);
  }
}

// Round 4
// 145.181 us; speedup vs baseline: 1.3934x; 1.3934x over previous
//
#include <hip/hip_runtime.h>
#include <cstdint>
#include <cstddef>

// Problem: B=32, S=2048, D=512, H=512
//   sb[b,h]   = state @ W1[:D]
//   h         = tanh(tanh(sb + input@W1[D:]))   <-- DOUBLE tanh (reference quirk)
//   logit[b,s]= sum_h h * w2[h]  - 1e30*(1-mask)
//   p = softmax over S;  pooled[b,d] = sum_s p*input
// Outputs: pooled (16384 f32) ++ logit (65536 f32)

#define NEG_BIG 1e30f

typedef __attribute__((ext_vector_type(8))) short short8_t;   // 8 x bf16
typedef __attribute__((ext_vector_type(4))) float f32x4;

__device__ inline unsigned short f2bf(float f){
  union { float f; unsigned int u; } v; v.f = f;
  unsigned int r = v.u + 0x7fffu + ((v.u >> 16) & 1u);   // RNE
  return (unsigned short)(r >> 16);
}
__device__ inline float bf2f(unsigned int lo16){
  union { unsigned int u; float f; } v; v.u = lo16 << 16; return v.f;
}
__device__ inline float tanh_fast(float x){
  x = fminf(fmaxf(x, -15.0f), 15.0f);
  float e = __expf(2.0f * x);
  return (e - 1.0f) / (e + 1.0f);
}

typedef __attribute__((address_space(1))) const unsigned int g_u32;
typedef __attribute__((address_space(3))) unsigned int l_u32;
__device__ inline void gload16(const unsigned short* g, unsigned short* l){
  __builtin_amdgcn_global_load_lds((g_u32*)g, (l_u32*)l, 16, 0, 0);
}

// ---------------------------------------------------------------- K0: merged prologue
// blocks 0..63    : sb[b,h] = state[b,:] @ W1[:512,h]   (latency-bound, hides under cvt)
// blocks 64..127  : w1xt[h][k] = bf16(W1[512+k][h])     (64x64 tiled transpose)
// blocks 128..2175: inb = bf16(input)                   (HBM-bound, 192 MB)
__global__ __launch_bounds__(256) void k0_all(const float* __restrict__ input,
                                              const float* __restrict__ state,
                                              const float* __restrict__ W1,
                                              unsigned short* __restrict__ inb,
                                              float* __restrict__ sb,
                                              unsigned short* __restrict__ w1xt){
  const int bid = blockIdx.x, t = threadIdx.x;
  if (bid < 64) {
    // ---- sb: one h per thread, 8 loads in flight
    const int b = bid >> 1, h = (bid & 1)*256 + t;
    __shared__ float st[512];
    st[t]       = state[b*512 + t];
    st[t + 256] = state[b*512 + t + 256];
    __syncthreads();
    float acc = 0.f;
    #pragma unroll 8
    for (int d = 0; d < 512; ++d) acc += st[d] * W1[(size_t)d*512 + h];
    sb[b*512 + h] = acc;
  } else if (bid < 128) {
    // ---- W1x transpose -> bf16 [h][k]
    const int q  = bid - 64;
    const int k0 = (q >> 3) * 64, h0 = (q & 7) * 64;
    __shared__ float tile[64][65];
    const int c = t & 63, r0 = t >> 6;
    #pragma unroll
    for (int i = 0; i < 16; ++i){
      int r = r0 + 4*i;
      tile[r][c] = W1[(size_t)(512 + k0 + r)*512 + h0 + c];
    }
    __syncthreads();
    #pragma unroll
    for (int i = 0; i < 16; ++i){
      int r = r0 + 4*i;
      w1xt[(size_t)(h0 + r)*512 + k0 + c] = f2bf(tile[c][r]);
    }
  } else {
    // ---- input -> bf16 copy
    const int tid = (bid - 128)*256 + t;              // 524288 threads
    const float4* in4 = (const float4*)input;
    ushort4* o4 = (ushort4*)inb;
    #pragma unroll
    for (int it = 0; it < 16; ++it){
      const size_t i = (size_t)it*524288 + tid;       // 8388608 float4 total
      const float4 v = in4[i];
      ushort4 o; o.x=f2bf(v.x); o.y=f2bf(v.y); o.z=f2bf(v.z); o.w=f2bf(v.w);
      o4[i] = o;
    }
  }
}

// ---------------------------------------------------------------- K1 fast: gload_lds GEMM
// LDS layout: linear [128 rows][8 chunks of 16B]; physical chunk = logical ^ (row&7).
// Staged with linear LDS dest + inverse-swizzled per-lane GLOBAL source (rule #21).
__global__ __launch_bounds__(256) void k1_gemm_fast(const unsigned short* __restrict__ inb,
                                                    const unsigned short* __restrict__ w1xt,
                                                    const float* __restrict__ sb,
                                                    const float* __restrict__ w2,
                                                    float* __restrict__ plog){
  __shared__ unsigned short lds_a[128*64];
  __shared__ unsigned short lds_b[128*64];

  const int orig = blockIdx.x;                 // XCD-grouped swizzle
  const int xcd  = orig & 7, slot = orig >> 3;
  const int mtile = xcd*64 + (slot >> 2);
  const int nt    = slot & 3;
  const int m0 = mtile * 128, n0 = nt * 128;
  const int b  = m0 >> 11;

  const int t = threadIdx.x;
  const int lane = t & 63, wid = t >> 6;
  const int wr = wid >> 1, wc = wid & 1;
  const int lr = lane & 15, kg = lane >> 4;
  const int l7 = lr & 7;

  const int srow = wid*32 + (lane >> 3);                    // 0..127
  const int scol = ((lane & 7) ^ ((lane >> 3) & 7)) * 8;    // inverse-swizzled source chunk
  const unsigned short* gA = inb  + (size_t)(m0 + srow)*512 + scol;
  const unsigned short* gB = w1xt + (size_t)(n0 + srow)*512 + scol;
  unsigned short* lA = &lds_a[(wid*4)*512];
  unsigned short* lB = &lds_b[(wid*4)*512];

  const unsigned short* rA0 = &lds_a[(wr*64 + lr)*64 + ((kg    ) ^ l7)*8]; // ks=0
  const unsigned short* rA1 = &lds_a[(wr*64 + lr)*64 + ((4 + kg) ^ l7)*8]; // ks=32
  const unsigned short* rB0 = &lds_b[(wc*64 + lr)*64 + ((kg    ) ^ l7)*8];
  const unsigned short* rB1 = &lds_b[(wc*64 + lr)*64 + ((4 + kg) ^ l7)*8];

  f32x4 acc[4][4];
  #pragma unroll
  for (int mi = 0; mi < 4; ++mi)
    #pragma unroll
    for (int ni = 0; ni < 4; ++ni) acc[mi][ni] = (f32x4){0.f,0.f,0.f,0.f};

  for (int kk = 0; kk < 512; kk += 64){
    #pragma unroll
    for (int i = 0; i < 4; ++i) gload16(gA + kk + i*8*512, lA + i*512);
    #pragma unroll
    for (int i = 0; i < 4; ++i) gload16(gB + kk + i*8*512, lB + i*512);
    __syncthreads();

    short8_t af[4], bfr[4];
    #pragma unroll
    for (int mi = 0; mi < 4; ++mi) af[mi]  = *(const short8_t*)(rA0 + mi*1024);
    #pragma unroll
    for (int ni = 0; ni < 4; ++ni) bfr[ni] = *(const short8_t*)(rB0 + ni*1024);
    #pragma unroll
    for (int mi = 0; mi < 4; ++mi)
      #pragma unroll
      for (int ni = 0; ni < 4; ++ni)
        acc[mi][ni] = __builtin_amdgcn_mfma_f32_16x16x32_bf16(af[mi], bfr[ni], acc[mi][ni], 0, 0, 0);
    #pragma unroll
    for (int mi = 0; mi < 4; ++mi) af[mi]  = *(const short8_t*)(rA1 + mi*1024);
    #pragma unroll
    for (int ni = 0; ni < 4; ++ni) bfr[ni] = *(const short8_t*)(rB1 + ni*1024);
    #pragma unroll
    for (int mi = 0; mi < 4; ++mi)
      #pragma unroll
      for (int ni = 0; ni < 4; ++ni)
        acc[mi][ni] = __builtin_amdgcn_mfma_f32_16x16x32_bf16(af[mi], bfr[ni], acc[mi][ni], 0, 0, 0);
    __syncthreads();
  }

  // epilogue: tanh(tanh(acc + sb)) * w2, reduce over 128 h-cols of this block
  float w2v[4], sbv[4];
  #pragma unroll
  for (int ni = 0; ni < 4; ++ni){
    const int h = n0 + wc*64 + ni*16 + lr;
    w2v[ni] = w2[h];
    sbv[ni] = sb[b*512 + h];
  }
  float* red = reinterpret_cast<float*>(&lds_a[0]);
  #pragma unroll
  for (int mi = 0; mi < 4; ++mi){
    #pragma unroll
    for (int j = 0; j < 4; ++j){
      float v = 0.f;
      #pragma unroll
      for (int ni = 0; ni < 4; ++ni)
        v += tanh_fast(tanh_fast(acc[mi][ni][j] + sbv[ni])) * w2v[ni];
      v += __shfl_xor(v, 1); v += __shfl_xor(v, 2);
      v += __shfl_xor(v, 4); v += __shfl_xor(v, 8);
      if (lr == 0){
        const int rloc = wr*64 + mi*16 + kg*4 + j;    // C/D row=(lane>>4)*4+j
        red[wc*128 + rloc] = v;
      }
    }
  }
  __syncthreads();
  if (t < 128) plog[(size_t)nt*65536 + m0 + t] = red[t] + red[128 + t];
}

// ---------------------------------------------------------------- K1 fallback (reg-staged, pad-72)
__global__ __launch_bounds__(256) void k1_gemm_fb(const float* __restrict__ input,
                                                  const unsigned short* __restrict__ w1xt,
                                                  const float* __restrict__ sb,
                                                  const float* __restrict__ w2,
                                                  float* __restrict__ plog){
  __shared__ unsigned short lds_a[128][72];
  __shared__ unsigned short lds_b[128][72];
  const int orig = blockIdx.x;
  const int xcd  = orig & 7, slot = orig >> 3;
  const int mtile = xcd*64 + (slot >> 2);
  const int nt    = slot & 3;
  const int m0 = mtile * 128, n0 = nt * 128;
  const int b  = m0 >> 11;
  const int t = threadIdx.x;
  const int lane = t & 63, wid = t >> 6;
  const int wr = wid >> 1, wc = wid & 1;
  const int lr = lane & 15, kg = lane >> 4;
  f32x4 acc[4][4];
  #pragma unroll
  for (int mi = 0; mi < 4; ++mi)
    #pragma unroll
    for (int ni = 0; ni < 4; ++ni) acc[mi][ni] = (f32x4){0.f,0.f,0.f,0.f};
  const int ar0 = t >> 4, afo = t & 15;
  const int br0 = t >> 3, bho = t & 7;
  for (int kk = 0; kk < 512; kk += 64){
    #pragma unroll
    for (int rr = 0; rr < 8; ++rr){
      const int r = ar0 + rr*16;
      const float4 v = *reinterpret_cast<const float4*>(input + (size_t)(m0 + r)*512 + kk + afo*4);
      ushort4 bv; bv.x=f2bf(v.x); bv.y=f2bf(v.y); bv.z=f2bf(v.z); bv.w=f2bf(v.w);
      *reinterpret_cast<ushort4*>(&lds_a[r][afo*4]) = bv;
    }
    #pragma unroll
    for (int rr = 0; rr < 4; ++rr){
      const int r = br0 + rr*32;
      const uint4 v = *reinterpret_cast<const uint4*>(w1xt + (size_t)(n0 + r)*512 + kk + bho*8);
      *reinterpret_cast<uint4*>(&lds_b[r][bho*8]) = v;
    }
    __syncthreads();
    #pragma unroll
    for (int ks = 0; ks < 64; ks += 32){
      short8_t af[4], bfr[4];
      #pragma unroll
      for (int mi = 0; mi < 4; ++mi)
        af[mi] = *reinterpret_cast<const short8_t*>(&lds_a[wr*64 + mi*16 + lr][ks + kg*8]);
      #pragma unroll
      for (int ni = 0; ni < 4; ++ni)
        bfr[ni] = *reinterpret_cast<const short8_t*>(&lds_b[wc*64 + ni*16 + lr][ks + kg*8]);
      #pragma unroll
      for (int mi = 0; mi < 4; ++mi)
        #pragma unroll
        for (int ni = 0; ni < 4; ++ni)
          acc[mi][ni] = __builtin_amdgcn_mfma_f32_16x16x32_bf16(af[mi], bfr[ni], acc[mi][ni], 0, 0, 0);
    }
    __syncthreads();
  }
  float w2v[4], sbv[4];
  #pragma unroll
  for (int ni = 0; ni < 4; ++ni){
    const int h = n0 + wc*64 + ni*16 + lr;
    w2v[ni] = w2[h]; sbv[ni] = sb[b*512 + h];
  }
  float* red = reinterpret_cast<float*>(&lds_a[0][0]);
  #pragma unroll
  for (int mi = 0; mi < 4; ++mi){
    #pragma unroll
    for (int j = 0; j < 4; ++j){
      float v = 0.f;
      #pragma unroll
      for (int ni = 0; ni < 4; ++ni)
        v += tanh_fast(tanh_fast(acc[mi][ni][j] + sbv[ni])) * w2v[ni];
      v += __shfl_xor(v, 1); v += __shfl_xor(v, 2);
      v += __shfl_xor(v, 4); v += __shfl_xor(v, 8);
      if (lr == 0){
        const int rloc = wr*64 + mi*16 + kg*4 + j;
        red[wc*128 + rloc] = v;
      }
    }
  }
  __syncthreads();
  if (t < 128) plog[(size_t)nt*65536 + m0 + t] = red[t] + red[128 + t];
}

// ---------------------------------------------------------------- K2: softmax stats
__global__ __launch_bounds__(256) void k2_softmax(const float* __restrict__ plog,
                                                  const float* __restrict__ mask,
                                                  float* __restrict__ out_logit,
                                                  float* __restrict__ mz){
  const int b = blockIdx.x, t = threadIdx.x;
  float l[8]; float mx = -3.4e38f;
  #pragma unroll
  for (int i = 0; i < 8; ++i){
    const size_t idx = (size_t)b*2048 + t + i*256;
    float v = plog[idx] + plog[65536 + idx] + plog[2*65536 + idx] + plog[3*65536 + idx];
    v -= NEG_BIG * (1.0f - mask[idx]);
    l[i] = v;
    out_logit[idx] = v;
    mx = fmaxf(mx, v);
  }
  __shared__ float red[8];
  const int wid = t >> 6, lane = t & 63;
  #pragma unroll
  for (int off = 1; off < 64; off <<= 1) mx = fmaxf(mx, __shfl_xor(mx, off));
  if (lane == 0) red[wid] = mx;
  __syncthreads();
  mx = fmaxf(fmaxf(red[0], red[1]), fmaxf(red[2], red[3]));
  float zs = 0.f;
  #pragma unroll
  for (int i = 0; i < 8; ++i) zs += __expf(l[i] - mx);
  #pragma unroll
  for (int off = 1; off < 64; off <<= 1) zs += __shfl_xor(zs, off);
  if (lane == 0) red[4 + wid] = zs;
  __syncthreads();
  if (t == 0){ mz[b*2] = mx; mz[b*2+1] = red[4]+red[5]+red[6]+red[7]; }
}

// ---------------------------------------------------------------- K3 fast: pool from bf16
__global__ __launch_bounds__(256) void k3_pool_bf(const unsigned short* __restrict__ inb,
                                                  const float* __restrict__ logit,
                                                  const float* __restrict__ mz,
                                                  float* __restrict__ pool){
  const int b = blockIdx.x >> 4, sc = blockIdx.x & 15;
  const int t = threadIdx.x;
  __shared__ float p[128];
  const float m = mz[b*2], invZ = 1.0f / mz[b*2+1];
  if (t < 128) p[t] = __expf(logit[(size_t)b*2048 + sc*128 + t] - m) * invZ;
  __syncthreads();
  const int half = t >> 7, cw = t & 127;
  float a0=0.f,a1=0.f,a2=0.f,a3=0.f;
  const unsigned short* base = inb + ((size_t)b*2048 + sc*128 + half)*512 + cw*4;
  #pragma unroll 4
  for (int i = 0; i < 64; ++i){
    const ushort4 v = *reinterpret_cast<const ushort4*>(base + (size_t)i*1024);
    const float pv = p[half + 2*i];
    a0 += pv*bf2f(v.x); a1 += pv*bf2f(v.y); a2 += pv*bf2f(v.z); a3 += pv*bf2f(v.w);
  }
  float4 o = {a0,a1,a2,a3};
  *reinterpret_cast<float4*>(pool + (size_t)blockIdx.x*1024 + half*512 + cw*4) = o;
}

// ---------------------------------------------------------------- K3 fallback: fp32 input
__global__ __launch_bounds__(256) void k3_pool_f32(const float* __restrict__ input,
                                                   const float* __restrict__ logit,
                                                   const float* __restrict__ mz,
                                                   float* __restrict__ pool){
  const int b = blockIdx.x >> 4, sc = blockIdx.x & 15;
  const int t = threadIdx.x;
  __shared__ float p[128];
  const float m = mz[b*2], invZ = 1.0f / mz[b*2+1];
  if (t < 128) p[t] = __expf(logit[(size_t)b*2048 + sc*128 + t] - m) * invZ;
  __syncthreads();
  float a0 = 0.f, a1 = 0.f;
  const float* base = input + ((size_t)b*2048 + sc*128)*512 + 2*t;
  #pragma unroll 4
  for (int i = 0; i < 128; ++i){
    const float2 v = *reinterpret_cast<const float2*>(base + (size_t)i*512);
    a0 += p[i]*v.x; a1 += p[i]*v.y;
  }
  pool[(size_t)blockIdx.x*512 + 2*t]     = a0;
  pool[(size_t)blockIdx.x*512 + 2*t + 1] = a1;
}

// ---------------------------------------------------------------- K4: reduce partials
__global__ __launch_bounds__(256) void k4_reduce(const float* __restrict__ pool,
                                                 float* __restrict__ out_pooled,
                                                 int nchunks){
  const int tg = blockIdx.x*256 + threadIdx.x;  // 0..16383
  const int b = tg >> 9, d = tg & 511;
  float s = 0.f;
  for (int c = 0; c < nchunks; ++c) s += pool[((size_t)b*nchunks + c)*512 + d];
  out_pooled[tg] = s;
}

// ---------------------------------------------------------------- launch
extern "C" void kernel_launch(void* const* d_in, const int* in_sizes, int n_in,
                              void* d_out, int out_size, void* d_ws, size_t ws_size,
                              hipStream_t stream){
  const float* input = (const float*)d_in[0];
  const float* state = (const float*)d_in[1];
  const float* mask  = (const float*)d_in[2];
  const float* W1    = (const float*)d_in[3];
  const float* w2    = (const float*)d_in[4];

  float* out_pooled = (float*)d_out;
  float* out_logit  = (float*)d_out + 16384;

  char* ws = (char*)d_ws;
  const size_t NEED_FAST = 67108864ull + 65536 + 524288 + 1048576 + 256 + 2097152;

  if (ws_size >= NEED_FAST){
    unsigned short* inb  = (unsigned short*)(ws);                          // 64 MB
    float*          sb   = (float*)(ws + 67108864);                        // 64 KB
    unsigned short* w1xt = (unsigned short*)(ws + 67108864 + 65536);       // 512 KB
    float*          plog = (float*)(ws + 67108864 + 589824);               // 1 MB
    float*          mz   = (float*)(ws + 67108864 + 1638400);              // 256 B
    float*          pool = (float*)(ws + 67108864 + 1638656);              // 2 MB

    k0_all      <<<2176, 256, 0, stream>>>(input, state, W1, inb, sb, w1xt);
    k1_gemm_fast<<<2048, 256, 0, stream>>>(inb, w1xt, sb, w2, plog);
    k2_softmax  <<<32,   256, 0, stream>>>(plog, mask, out_logit, mz);
    k3_pool_bf  <<<512,  256, 0, stream>>>(inb, out_logit, mz, pool);
    k4_reduce   <<<64,   256, 0, stream>>>(pool, out_pooled, 32);
  } else {
    float*          sb   = (float*)(ws);
    unsigned short* w1xt = (unsigned short*)(ws + 65536);
    float*          plog = (float*)(ws + 65536 + 524288);
    float*          mz   = (float*)(ws + 65536 + 524288 + 1048576);
    float*          pool = (float*)(ws + 65536 + 524288 + 1048576 + 256);

    // fallback keeps the old small-ws path (k0 split kernels not needed: reuse k0_all layout)
    k0_all    <<<128,  256, 0, stream>>>(nullptr, state, W1, nullptr, sb, w1xt); // blocks <128 only touch state/W1
    k1_gemm_fb<<<2048, 256, 0, stream>>>(input, w1xt, sb, w2, plog);
    k2_softmax<<<32,   256, 0, stream>>>(plog, mask, out_logit, mz);
    k3_pool_f32<<<512, 256, 0, stream>>>(input, out_logit, mz, pool);
    k4_reduce <<<64,   256, 0, stream>>>(pool, out_pooled, 16);
  }
}

// Round 5
// 134.559 us; speedup vs baseline: 1.5034x; 1.0789x over previous
//
#include <hip/hip_runtime.h>
#include <cstdint>
#include <cstddef>

// Problem: B=32, S=2048, D=512, H=512
//   sb[b,h]   = state @ W1[:D]
//   h         = tanh(tanh(sb + input@W1[D:]))   <-- DOUBLE tanh (reference quirk)
//   logit[b,s]= sum_h h * w2[h]  - 1e30*(1-mask)
//   p = softmax over S;  pooled[b,d] = sum_s p*input
// Outputs: pooled (16384 f32) ++ logit (65536 f32)

#define NEG_BIG 1e30f

typedef __attribute__((ext_vector_type(8))) short short8_t;   // 8 x bf16
typedef __attribute__((ext_vector_type(4))) float f32x4;

__device__ inline unsigned short f2bf(float f){
  union { float f; unsigned int u; } v; v.f = f;
  unsigned int r = v.u + 0x7fffu + ((v.u >> 16) & 1u);   // RNE
  return (unsigned short)(r >> 16);
}
__device__ inline float bf2f(unsigned int lo16){
  union { unsigned int u; float f; } v; v.u = lo16 << 16; return v.f;
}
__device__ inline float tanh_fast(float x){
  x = fminf(fmaxf(x, -15.0f), 15.0f);
  float e = __expf(2.0f * x);
  return (e - 1.0f) / (e + 1.0f);
}

typedef __attribute__((address_space(1))) const unsigned int g_u32;
typedef __attribute__((address_space(3))) unsigned int l_u32;
__device__ inline void gload16(const unsigned short* g, unsigned short* l){
  __builtin_amdgcn_global_load_lds((g_u32*)g, (l_u32*)l, 16, 0, 0);
}

// ---------------------------------------------------------------- K0: merged prologue
// blocks [0, ncvt)           : inb = bf16(input)                (HBM-bound bulk)
// blocks [ncvt, ncvt+64)     : w1xt[h][k] = bf16(W1[512+k][h])  (transpose)
// blocks [ncvt+64, ncvt+320) : sbp[ds][b][h] partial state@W1s  (d-split: 8 slices x 32 b)
__global__ __launch_bounds__(256) void k0_all(const float* __restrict__ input,
                                              const float* __restrict__ state,
                                              const float* __restrict__ W1,
                                              unsigned short* __restrict__ inb,
                                              float* __restrict__ sbp,
                                              unsigned short* __restrict__ w1xt,
                                              int ncvt){
  const int bid = blockIdx.x, t = threadIdx.x;
  if (bid < ncvt) {
    // ---- input -> bf16 copy (2048 blocks)
    const int tid = bid*256 + t;
    const float4* in4 = (const float4*)input;
    ushort4* o4 = (ushort4*)inb;
    #pragma unroll
    for (int it = 0; it < 16; ++it){
      const size_t i = (size_t)it*524288 + tid;       // 8388608 float4 total
      const float4 v = in4[i];
      ushort4 o; o.x=f2bf(v.x); o.y=f2bf(v.y); o.z=f2bf(v.z); o.w=f2bf(v.w);
      o4[i] = o;
    }
  } else if (bid < ncvt + 64) {
    // ---- W1x transpose -> bf16 [h][k]
    const int q  = bid - ncvt;
    const int k0 = (q >> 3) * 64, h0 = (q & 7) * 64;
    __shared__ float tile[64][65];
    const int c = t & 63, r0 = t >> 6;
    #pragma unroll
    for (int i = 0; i < 16; ++i){
      int r = r0 + 4*i;
      tile[r][c] = W1[(size_t)(512 + k0 + r)*512 + h0 + c];
    }
    __syncthreads();
    #pragma unroll
    for (int i = 0; i < 16; ++i){
      int r = r0 + 4*i;
      w1xt[(size_t)(h0 + r)*512 + k0 + c] = f2bf(tile[c][r]);
    }
  } else {
    // ---- sb partials: block = (b, d-slice of 64); thread t covers h=t and h=t+256
    const int idx = bid - ncvt - 64;        // 0..255
    const int b = idx >> 3, ds = idx & 7;
    __shared__ float stl[64];
    if (t < 64) stl[t] = state[b*512 + ds*64 + t];
    __syncthreads();
    float acc0 = 0.f, acc1 = 0.f;
    #pragma unroll 8
    for (int i = 0; i < 64; ++i){
      const float w = stl[i];
      acc0 += w * W1[(size_t)(ds*64 + i)*512 + t];
      acc1 += w * W1[(size_t)(ds*64 + i)*512 + t + 256];
    }
    sbp[(size_t)(ds*32 + b)*512 + t]       = acc0;
    sbp[(size_t)(ds*32 + b)*512 + t + 256] = acc1;
  }
}

// ---------------------------------------------------------------- K1 fast: gload_lds GEMM
// LDS layout: linear [128 rows][8 chunks of 16B]; physical chunk = logical ^ (row&7).
// Staged with linear LDS dest + inverse-swizzled per-lane GLOBAL source (rule #21).
__global__ __launch_bounds__(256) void k1_gemm_fast(const unsigned short* __restrict__ inb,
                                                    const unsigned short* __restrict__ w1xt,
                                                    const float* __restrict__ sbp,
                                                    const float* __restrict__ w2,
                                                    float* __restrict__ plog){
  __shared__ unsigned short lds_a[128*64];
  __shared__ unsigned short lds_b[128*64];

  const int orig = blockIdx.x;                 // XCD-grouped swizzle
  const int xcd  = orig & 7, slot = orig >> 3;
  const int mtile = xcd*64 + (slot >> 2);
  const int nt    = slot & 3;
  const int m0 = mtile * 128, n0 = nt * 128;
  const int b  = m0 >> 11;

  const int t = threadIdx.x;
  const int lane = t & 63, wid = t >> 6;
  const int wr = wid >> 1, wc = wid & 1;
  const int lr = lane & 15, kg = lane >> 4;
  const int l7 = lr & 7;

  const int srow = wid*32 + (lane >> 3);                    // 0..127
  const int scol = ((lane & 7) ^ ((lane >> 3) & 7)) * 8;    // inverse-swizzled source chunk
  const unsigned short* gA = inb  + (size_t)(m0 + srow)*512 + scol;
  const unsigned short* gB = w1xt + (size_t)(n0 + srow)*512 + scol;
  unsigned short* lA = &lds_a[(wid*4)*512];
  unsigned short* lB = &lds_b[(wid*4)*512];

  const unsigned short* rA0 = &lds_a[(wr*64 + lr)*64 + ((kg    ) ^ l7)*8]; // ks=0
  const unsigned short* rA1 = &lds_a[(wr*64 + lr)*64 + ((4 + kg) ^ l7)*8]; // ks=32
  const unsigned short* rB0 = &lds_b[(wc*64 + lr)*64 + ((kg    ) ^ l7)*8];
  const unsigned short* rB1 = &lds_b[(wc*64 + lr)*64 + ((4 + kg) ^ l7)*8];

  f32x4 acc[4][4];
  #pragma unroll
  for (int mi = 0; mi < 4; ++mi)
    #pragma unroll
    for (int ni = 0; ni < 4; ++ni) acc[mi][ni] = (f32x4){0.f,0.f,0.f,0.f};

  for (int kk = 0; kk < 512; kk += 64){
    #pragma unroll
    for (int i = 0; i < 4; ++i) gload16(gA + kk + i*8*512, lA + i*512);
    #pragma unroll
    for (int i = 0; i < 4; ++i) gload16(gB + kk + i*8*512, lB + i*512);
    __syncthreads();

    short8_t af[4], bfr[4];
    #pragma unroll
    for (int mi = 0; mi < 4; ++mi) af[mi]  = *(const short8_t*)(rA0 + mi*1024);
    #pragma unroll
    for (int ni = 0; ni < 4; ++ni) bfr[ni] = *(const short8_t*)(rB0 + ni*1024);
    #pragma unroll
    for (int mi = 0; mi < 4; ++mi)
      #pragma unroll
      for (int ni = 0; ni < 4; ++ni)
        acc[mi][ni] = __builtin_amdgcn_mfma_f32_16x16x32_bf16(af[mi], bfr[ni], acc[mi][ni], 0, 0, 0);
    #pragma unroll
    for (int mi = 0; mi < 4; ++mi) af[mi]  = *(const short8_t*)(rA1 + mi*1024);
    #pragma unroll
    for (int ni = 0; ni < 4; ++ni) bfr[ni] = *(const short8_t*)(rB1 + ni*1024);
    #pragma unroll
    for (int mi = 0; mi < 4; ++mi)
      #pragma unroll
      for (int ni = 0; ni < 4; ++ni)
        acc[mi][ni] = __builtin_amdgcn_mfma_f32_16x16x32_bf16(af[mi], bfr[ni], acc[mi][ni], 0, 0, 0);
    __syncthreads();
  }

  // epilogue: tanh(tanh(acc + sb)) * w2; sb = sum of 8 d-slice partials
  float w2v[4], sbv[4];
  #pragma unroll
  for (int ni = 0; ni < 4; ++ni){
    const int h = n0 + wc*64 + ni*16 + lr;
    w2v[ni] = w2[h];
    float s = 0.f;
    #pragma unroll
    for (int ds = 0; ds < 8; ++ds) s += sbp[(size_t)(ds*32 + b)*512 + h];
    sbv[ni] = s;
  }
  float* red = reinterpret_cast<float*>(&lds_a[0]);
  #pragma unroll
  for (int mi = 0; mi < 4; ++mi){
    #pragma unroll
    for (int j = 0; j < 4; ++j){
      float v = 0.f;
      #pragma unroll
      for (int ni = 0; ni < 4; ++ni)
        v += tanh_fast(tanh_fast(acc[mi][ni][j] + sbv[ni])) * w2v[ni];
      v += __shfl_xor(v, 1); v += __shfl_xor(v, 2);
      v += __shfl_xor(v, 4); v += __shfl_xor(v, 8);
      if (lr == 0){
        const int rloc = wr*64 + mi*16 + kg*4 + j;    // C/D row=(lane>>4)*4+j
        red[wc*128 + rloc] = v;
      }
    }
  }
  __syncthreads();
  if (t < 128) plog[(size_t)nt*65536 + m0 + t] = red[t] + red[128 + t];
}

// ---------------------------------------------------------------- K1 fallback (reg-staged, pad-72)
__global__ __launch_bounds__(256) void k1_gemm_fb(const float* __restrict__ input,
                                                  const unsigned short* __restrict__ w1xt,
                                                  const float* __restrict__ sbp,
                                                  const float* __restrict__ w2,
                                                  float* __restrict__ plog){
  __shared__ unsigned short lds_a[128][72];
  __shared__ unsigned short lds_b[128][72];
  const int orig = blockIdx.x;
  const int xcd  = orig & 7, slot = orig >> 3;
  const int mtile = xcd*64 + (slot >> 2);
  const int nt    = slot & 3;
  const int m0 = mtile * 128, n0 = nt * 128;
  const int b  = m0 >> 11;
  const int t = threadIdx.x;
  const int lane = t & 63, wid = t >> 6;
  const int wr = wid >> 1, wc = wid & 1;
  const int lr = lane & 15, kg = lane >> 4;
  f32x4 acc[4][4];
  #pragma unroll
  for (int mi = 0; mi < 4; ++mi)
    #pragma unroll
    for (int ni = 0; ni < 4; ++ni) acc[mi][ni] = (f32x4){0.f,0.f,0.f,0.f};
  const int ar0 = t >> 4, afo = t & 15;
  const int br0 = t >> 3, bho = t & 7;
  for (int kk = 0; kk < 512; kk += 64){
    #pragma unroll
    for (int rr = 0; rr < 8; ++rr){
      const int r = ar0 + rr*16;
      const float4 v = *reinterpret_cast<const float4*>(input + (size_t)(m0 + r)*512 + kk + afo*4);
      ushort4 bv; bv.x=f2bf(v.x); bv.y=f2bf(v.y); bv.z=f2bf(v.z); bv.w=f2bf(v.w);
      *reinterpret_cast<ushort4*>(&lds_a[r][afo*4]) = bv;
    }
    #pragma unroll
    for (int rr = 0; rr < 4; ++rr){
      const int r = br0 + rr*32;
      const uint4 v = *reinterpret_cast<const uint4*>(w1xt + (size_t)(n0 + r)*512 + kk + bho*8);
      *reinterpret_cast<uint4*>(&lds_b[r][bho*8]) = v;
    }
    __syncthreads();
    #pragma unroll
    for (int ks = 0; ks < 64; ks += 32){
      short8_t af[4], bfr[4];
      #pragma unroll
      for (int mi = 0; mi < 4; ++mi)
        af[mi] = *reinterpret_cast<const short8_t*>(&lds_a[wr*64 + mi*16 + lr][ks + kg*8]);
      #pragma unroll
      for (int ni = 0; ni < 4; ++ni)
        bfr[ni] = *reinterpret_cast<const short8_t*>(&lds_b[wc*64 + ni*16 + lr][ks + kg*8]);
      #pragma unroll
      for (int mi = 0; mi < 4; ++mi)
        #pragma unroll
        for (int ni = 0; ni < 4; ++ni)
          acc[mi][ni] = __builtin_amdgcn_mfma_f32_16x16x32_bf16(af[mi], bfr[ni], acc[mi][ni], 0, 0, 0);
    }
    __syncthreads();
  }
  float w2v[4], sbv[4];
  #pragma unroll
  for (int ni = 0; ni < 4; ++ni){
    const int h = n0 + wc*64 + ni*16 + lr;
    w2v[ni] = w2[h];
    float s = 0.f;
    #pragma unroll
    for (int ds = 0; ds < 8; ++ds) s += sbp[(size_t)(ds*32 + b)*512 + h];
    sbv[ni] = s;
  }
  float* red = reinterpret_cast<float*>(&lds_a[0][0]);
  #pragma unroll
  for (int mi = 0; mi < 4; ++mi){
    #pragma unroll
    for (int j = 0; j < 4; ++j){
      float v = 0.f;
      #pragma unroll
      for (int ni = 0; ni < 4; ++ni)
        v += tanh_fast(tanh_fast(acc[mi][ni][j] + sbv[ni])) * w2v[ni];
      v += __shfl_xor(v, 1); v += __shfl_xor(v, 2);
      v += __shfl_xor(v, 4); v += __shfl_xor(v, 8);
      if (lr == 0){
        const int rloc = wr*64 + mi*16 + kg*4 + j;
        red[wc*128 + rloc] = v;
      }
    }
  }
  __syncthreads();
  if (t < 128) plog[(size_t)nt*65536 + m0 + t] = red[t] + red[128 + t];
}

// ---------------------------------------------------------------- K2: softmax stats
__global__ __launch_bounds__(256) void k2_softmax(const float* __restrict__ plog,
                                                  const float* __restrict__ mask,
                                                  float* __restrict__ out_logit,
                                                  float* __restrict__ mz){
  const int b = blockIdx.x, t = threadIdx.x;
  float l[8]; float mx = -3.4e38f;
  #pragma unroll
  for (int i = 0; i < 8; ++i){
    const size_t idx = (size_t)b*2048 + t + i*256;
    float v = plog[idx] + plog[65536 + idx] + plog[2*65536 + idx] + plog[3*65536 + idx];
    v -= NEG_BIG * (1.0f - mask[idx]);
    l[i] = v;
    out_logit[idx] = v;
    mx = fmaxf(mx, v);
  }
  __shared__ float red[8];
  const int wid = t >> 6, lane = t & 63;
  #pragma unroll
  for (int off = 1; off < 64; off <<= 1) mx = fmaxf(mx, __shfl_xor(mx, off));
  if (lane == 0) red[wid] = mx;
  __syncthreads();
  mx = fmaxf(fmaxf(red[0], red[1]), fmaxf(red[2], red[3]));
  float zs = 0.f;
  #pragma unroll
  for (int i = 0; i < 8; ++i) zs += __expf(l[i] - mx);
  #pragma unroll
  for (int off = 1; off < 64; off <<= 1) zs += __shfl_xor(zs, off);
  if (lane == 0) red[4 + wid] = zs;
  __syncthreads();
  if (t == 0){ mz[b*2] = mx; mz[b*2+1] = red[4]+red[5]+red[6]+red[7]; }
}

// ---------------------------------------------------------------- K3 fast: pool from bf16
__global__ __launch_bounds__(256) void k3_pool_bf(const unsigned short* __restrict__ inb,
                                                  const float* __restrict__ logit,
                                                  const float* __restrict__ mz,
                                                  float* __restrict__ pool){
  const int b = blockIdx.x >> 4, sc = blockIdx.x & 15;
  const int t = threadIdx.x;
  __shared__ float p[128];
  const float m = mz[b*2], invZ = 1.0f / mz[b*2+1];
  if (t < 128) p[t] = __expf(logit[(size_t)b*2048 + sc*128 + t] - m) * invZ;
  __syncthreads();
  const int half = t >> 7, cw = t & 127;
  float a0=0.f,a1=0.f,a2=0.f,a3=0.f;
  const unsigned short* base = inb + ((size_t)b*2048 + sc*128 + half)*512 + cw*4;
  #pragma unroll 4
  for (int i = 0; i < 64; ++i){
    const ushort4 v = *reinterpret_cast<const ushort4*>(base + (size_t)i*1024);
    const float pv = p[half + 2*i];
    a0 += pv*bf2f(v.x); a1 += pv*bf2f(v.y); a2 += pv*bf2f(v.z); a3 += pv*bf2f(v.w);
  }
  float4 o = {a0,a1,a2,a3};
  *reinterpret_cast<float4*>(pool + (size_t)blockIdx.x*1024 + half*512 + cw*4) = o;
}

// ---------------------------------------------------------------- K3 fallback: fp32 input
__global__ __launch_bounds__(256) void k3_pool_f32(const float* __restrict__ input,
                                                   const float* __restrict__ logit,
                                                   const float* __restrict__ mz,
                                                   float* __restrict__ pool){
  const int b = blockIdx.x >> 4, sc = blockIdx.x & 15;
  const int t = threadIdx.x;
  __shared__ float p[128];
  const float m = mz[b*2], invZ = 1.0f / mz[b*2+1];
  if (t < 128) p[t] = __expf(logit[(size_t)b*2048 + sc*128 + t] - m) * invZ;
  __syncthreads();
  float a0 = 0.f, a1 = 0.f;
  const float* base = input + ((size_t)b*2048 + sc*128)*512 + 2*t;
  #pragma unroll 4
  for (int i = 0; i < 128; ++i){
    const float2 v = *reinterpret_cast<const float2*>(base + (size_t)i*512);
    a0 += p[i]*v.x; a1 += p[i]*v.y;
  }
  pool[(size_t)blockIdx.x*512 + 2*t]     = a0;
  pool[(size_t)blockIdx.x*512 + 2*t + 1] = a1;
}

// ---------------------------------------------------------------- K4: reduce partials
__global__ __launch_bounds__(256) void k4_reduce(const float* __restrict__ pool,
                                                 float* __restrict__ out_pooled,
                                                 int nchunks){
  const int tg = blockIdx.x*256 + threadIdx.x;  // 0..16383
  const int b = tg >> 9, d = tg & 511;
  float s = 0.f;
  for (int c = 0; c < nchunks; ++c) s += pool[((size_t)b*nchunks + c)*512 + d];
  out_pooled[tg] = s;
}

// ---------------------------------------------------------------- launch
extern "C" void kernel_launch(void* const* d_in, const int* in_sizes, int n_in,
                              void* d_out, int out_size, void* d_ws, size_t ws_size,
                              hipStream_t stream){
  const float* input = (const float*)d_in[0];
  const float* state = (const float*)d_in[1];
  const float* mask  = (const float*)d_in[2];
  const float* W1    = (const float*)d_in[3];
  const float* w2    = (const float*)d_in[4];

  float* out_pooled = (float*)d_out;
  float* out_logit  = (float*)d_out + 16384;

  char* ws = (char*)d_ws;
  // fast-path ws layout
  const size_t O_INB = 0;                    // 64 MB
  const size_t O_SBP = 67108864;             // 512 KB (8 x 32 x 512 f32)
  const size_t O_W1X = O_SBP + 524288;       // 512 KB
  const size_t O_PLG = O_W1X + 524288;       // 1 MB
  const size_t O_MZ  = O_PLG + 1048576;      // 256 B
  const size_t O_PL  = O_MZ  + 256;          // 2 MB
  const size_t NEED_FAST = O_PL + 2097152;

  if (ws_size >= NEED_FAST){
    unsigned short* inb  = (unsigned short*)(ws + O_INB);
    float*          sbp  = (float*)(ws + O_SBP);
    unsigned short* w1xt = (unsigned short*)(ws + O_W1X);
    float*          plog = (float*)(ws + O_PLG);
    float*          mz   = (float*)(ws + O_MZ);
    float*          pool = (float*)(ws + O_PL);

    k0_all      <<<2368, 256, 0, stream>>>(input, state, W1, inb, sbp, w1xt, 2048);
    k1_gemm_fast<<<2048, 256, 0, stream>>>(inb, w1xt, sbp, w2, plog);
    k2_softmax  <<<32,   256, 0, stream>>>(plog, mask, out_logit, mz);
    k3_pool_bf  <<<512,  256, 0, stream>>>(inb, out_logit, mz, pool);
    k4_reduce   <<<64,   256, 0, stream>>>(pool, out_pooled, 32);
  } else {
    float*          sbp  = (float*)(ws);                                   // 512 KB
    unsigned short* w1xt = (unsigned short*)(ws + 524288);                 // 512 KB
    float*          plog = (float*)(ws + 1048576);                         // 1 MB
    float*          mz   = (float*)(ws + 2097152);                         // 256 B
    float*          pool = (float*)(ws + 2097408);                         // 1 MB

    k0_all    <<<320,  256, 0, stream>>>(nullptr, state, W1, nullptr, sbp, w1xt, 0);
    k1_gemm_fb<<<2048, 256, 0, stream>>>(input, w1xt, sbp, w2, plog);
    k2_softmax<<<32,   256, 0, stream>>>(plog, mask, out_logit, mz);
    k3_pool_f32<<<512, 256, 0, stream>>>(input, out_logit, mz, pool);
    k4_reduce <<<64,   256, 0, stream>>>(pool, out_pooled, 16);
  }
}

// Round 6
// 124.406 us; speedup vs baseline: 1.6261x; 1.0816x over previous
//
#include <hip/hip_runtime.h>
#include <cstdint>
#include <cstddef>

// Problem: B=32, S=2048, D=512, H=512
//   sb[b,h]   = state @ W1[:D]
//   h         = tanh(tanh(sb + input@W1[D:]))   <-- DOUBLE tanh (reference quirk)
//   logit[b,s]= sum_h h * w2[h]  - 1e30*(1-mask)
//   p = softmax over S;  pooled[b,d] = sum_s p*input
// Outputs: pooled (16384 f32) ++ logit (65536 f32)

#define NEG_BIG 1e30f

typedef __attribute__((ext_vector_type(8))) short short8_t;   // 8 x bf16
typedef __attribute__((ext_vector_type(4))) float f32x4;

__device__ inline unsigned short f2bf(float f){
  union { float f; unsigned int u; } v; v.f = f;
  unsigned int r = v.u + 0x7fffu + ((v.u >> 16) & 1u);   // RNE
  return (unsigned short)(r >> 16);
}
__device__ inline float bf2f(unsigned int lo16){
  union { unsigned int u; float f; } v; v.u = lo16 << 16; return v.f;
}
// tanh via 1 - 2/(1+e^{2x}): exp overflow -> inf -> rcp -> 0 -> +1; underflow -> -1.
__device__ inline float tanh_cheap(float x){
  return 1.0f - 2.0f*__builtin_amdgcn_rcpf(1.0f + __expf(2.0f*x));
}

typedef __attribute__((address_space(1))) const unsigned int g_u32;
typedef __attribute__((address_space(3))) unsigned int l_u32;
__device__ inline void gload16(const unsigned short* g, unsigned short* l){
  __builtin_amdgcn_global_load_lds((g_u32*)g, (l_u32*)l, 16, 0, 0);
}

// ---------------------------------------------------------------- K0: merged prologue
// blocks [0, ncvt)           : inb = bf16(input)                (HBM-bound bulk)
// blocks [ncvt, ncvt+64)     : w1xt[h][k] = bf16(W1[512+k][h])  (transpose)
// blocks [ncvt+64, ncvt+320) : sbp[ds][b][h] partial state@W1s  (d-split: 8 slices x 32 b)
__global__ __launch_bounds__(256) void k0_all(const float* __restrict__ input,
                                              const float* __restrict__ state,
                                              const float* __restrict__ W1,
                                              unsigned short* __restrict__ inb,
                                              float* __restrict__ sbp,
                                              unsigned short* __restrict__ w1xt,
                                              int ncvt){
  const int bid = blockIdx.x, t = threadIdx.x;
  if (bid < ncvt) {
    const int tid = bid*256 + t;
    const float4* in4 = (const float4*)input;
    ushort4* o4 = (ushort4*)inb;
    #pragma unroll
    for (int it = 0; it < 16; ++it){
      const size_t i = (size_t)it*524288 + tid;       // 8388608 float4 total
      const float4 v = in4[i];
      ushort4 o; o.x=f2bf(v.x); o.y=f2bf(v.y); o.z=f2bf(v.z); o.w=f2bf(v.w);
      o4[i] = o;
    }
  } else if (bid < ncvt + 64) {
    const int q  = bid - ncvt;
    const int k0 = (q >> 3) * 64, h0 = (q & 7) * 64;
    __shared__ float tile[64][65];
    const int c = t & 63, r0 = t >> 6;
    #pragma unroll
    for (int i = 0; i < 16; ++i){
      int r = r0 + 4*i;
      tile[r][c] = W1[(size_t)(512 + k0 + r)*512 + h0 + c];
    }
    __syncthreads();
    #pragma unroll
    for (int i = 0; i < 16; ++i){
      int r = r0 + 4*i;
      w1xt[(size_t)(h0 + r)*512 + k0 + c] = f2bf(tile[c][r]);
    }
  } else {
    const int idx = bid - ncvt - 64;        // 0..255
    const int b = idx >> 3, ds = idx & 7;
    __shared__ float stl[64];
    if (t < 64) stl[t] = state[b*512 + ds*64 + t];
    __syncthreads();
    float acc0 = 0.f, acc1 = 0.f;
    #pragma unroll 8
    for (int i = 0; i < 64; ++i){
      const float w = stl[i];
      acc0 += w * W1[(size_t)(ds*64 + i)*512 + t];
      acc1 += w * W1[(size_t)(ds*64 + i)*512 + t + 256];
    }
    sbp[(size_t)(ds*32 + b)*512 + t]       = acc0;
    sbp[(size_t)(ds*32 + b)*512 + t + 256] = acc1;
  }
}

// ---------------------------------------------------------------- K1 fast: 2-phase pipelined GEMM
// BK=32, double-buffered (4 x 8KB LDS). Issue-early / wait-late: STAGE(next) ->
// COMPUTE(cur) -> __syncthreads (implicit vmcnt(0) waits loads that flew during compute).
// LDS chunk swizzle: phys16B = logical ^ ((row>>1)&3); realized via pre-swizzled
// global source (linear gload_lds dest) + swizzled ds_read addr (rule #21).
__global__ __launch_bounds__(256) void k1_gemm_fast(const unsigned short* __restrict__ inb,
                                                    const unsigned short* __restrict__ w1xt,
                                                    const float* __restrict__ sbp,
                                                    const float* __restrict__ w2,
                                                    float* __restrict__ plog){
  __shared__ unsigned short lds_a0[128*32];
  __shared__ unsigned short lds_a1[128*32];
  __shared__ unsigned short lds_b0[128*32];
  __shared__ unsigned short lds_b1[128*32];

  const int orig = blockIdx.x;                 // XCD-grouped swizzle
  const int xcd  = orig & 7, slot = orig >> 3;
  const int mtile = xcd*64 + (slot >> 2);
  const int nt    = slot & 3;
  const int m0 = mtile * 128, n0 = nt * 128;
  const int b  = m0 >> 11;

  const int t = threadIdx.x;
  const int lane = t & 63, wid = t >> 6;
  const int wr = wid >> 1, wc = wid & 1;
  const int lr = lane & 15, kg = lane >> 4;

  // ---- staging addresses: load i covers rows i*64 + wid*16 + (lane>>2), phys chunk lane&3
  const int sr = wid*16 + (lane >> 2);
  const int sl = ((lane & 3) ^ ((lane >> 3) & 3)) * 8;    // inverse-swizzled source k-offset
  const unsigned short* gA0 = inb  + (size_t)(m0 + sr)*512 + sl;
  const unsigned short* gA1 = gA0 + 64*512;
  const unsigned short* gB0 = w1xt + (size_t)(n0 + sr)*512 + sl;
  const unsigned short* gB1 = gB0 + 64*512;
  unsigned short* dA0_0 = &lds_a0[(wid*16)*32];      // + lane*8 elems implicit (HW)
  unsigned short* dA0_1 = &lds_a0[(64 + wid*16)*32];
  unsigned short* dA1_0 = &lds_a1[(wid*16)*32];
  unsigned short* dA1_1 = &lds_a1[(64 + wid*16)*32];
  unsigned short* dB0_0 = &lds_b0[(wid*16)*32];
  unsigned short* dB0_1 = &lds_b0[(64 + wid*16)*32];
  unsigned short* dB1_0 = &lds_b1[(wid*16)*32];
  unsigned short* dB1_1 = &lds_b1[(64 + wid*16)*32];

  // ---- fragment read bases: phys chunk = kg ^ ((row>>1)&3), row = *64/*16 + lr
  const int rsw = ((kg ^ ((lr >> 1) & 3)) * 8);
  const unsigned short* rA0 = &lds_a0[(wr*64 + lr)*32 + rsw];
  const unsigned short* rA1 = &lds_a1[(wr*64 + lr)*32 + rsw];
  const unsigned short* rB0 = &lds_b0[(wc*64 + lr)*32 + rsw];
  const unsigned short* rB1 = &lds_b1[(wc*64 + lr)*32 + rsw];

  f32x4 acc[4][4];
  #pragma unroll
  for (int mi = 0; mi < 4; ++mi)
    #pragma unroll
    for (int ni = 0; ni < 4; ++ni) acc[mi][ni] = (f32x4){0.f,0.f,0.f,0.f};

#define STAGE(dA_0,dA_1,dB_0,dB_1, koff) do{ \
    gload16(gA0 + (koff), dA_0); gload16(gA1 + (koff), dA_1); \
    gload16(gB0 + (koff), dB_0); gload16(gB1 + (koff), dB_1); }while(0)

#define COMPUTE(rA, rB) do{ \
    short8_t af[4], bfr[4]; \
    _Pragma("unroll") for (int mi = 0; mi < 4; ++mi) af[mi]  = *(const short8_t*)((rA) + mi*512); \
    _Pragma("unroll") for (int ni = 0; ni < 4; ++ni) bfr[ni] = *(const short8_t*)((rB) + ni*512); \
    _Pragma("unroll") for (int mi = 0; mi < 4; ++mi) \
      _Pragma("unroll") for (int ni = 0; ni < 4; ++ni) \
        acc[mi][ni] = __builtin_amdgcn_mfma_f32_16x16x32_bf16(af[mi], bfr[ni], acc[mi][ni], 0, 0, 0); }while(0)

  STAGE(dA0_0,dA0_1,dB0_0,dB0_1, 0);
  __syncthreads();
  for (int it = 0; it < 16; it += 2){
    STAGE(dA1_0,dA1_1,dB1_0,dB1_1, (it+1)*32);   // issue next (flies during compute)
    COMPUTE(rA0, rB0);
    __syncthreads();                              // vmcnt(0): next-stage had compute-time in flight
    if (it + 2 < 16) STAGE(dA0_0,dA0_1,dB0_0,dB0_1, (it+2)*32);
    COMPUTE(rA1, rB1);
    __syncthreads();
  }
#undef STAGE
#undef COMPUTE

  // epilogue: tanh(tanh(acc + sb)) * w2; sb = sum of 8 d-slice partials
  float w2v[4], sbv[4];
  #pragma unroll
  for (int ni = 0; ni < 4; ++ni){
    const int h = n0 + wc*64 + ni*16 + lr;
    w2v[ni] = w2[h];
    float s = 0.f;
    #pragma unroll
    for (int ds = 0; ds < 8; ++ds) s += sbp[(size_t)(ds*32 + b)*512 + h];
    sbv[ni] = s;
  }
  float* red = reinterpret_cast<float*>(&lds_a0[0]);
  #pragma unroll
  for (int mi = 0; mi < 4; ++mi){
    #pragma unroll
    for (int j = 0; j < 4; ++j){
      float v = 0.f;
      #pragma unroll
      for (int ni = 0; ni < 4; ++ni)
        v += tanh_cheap(tanh_cheap(acc[mi][ni][j] + sbv[ni])) * w2v[ni];
      v += __shfl_xor(v, 1); v += __shfl_xor(v, 2);
      v += __shfl_xor(v, 4); v += __shfl_xor(v, 8);
      if (lr == 0){
        const int rloc = wr*64 + mi*16 + kg*4 + j;    // C/D row=(lane>>4)*4+j
        red[wc*128 + rloc] = v;
      }
    }
  }
  __syncthreads();
  if (t < 128) plog[(size_t)nt*65536 + m0 + t] = red[t] + red[128 + t];
}

// ---------------------------------------------------------------- K1 fallback (reg-staged, pad-72)
__global__ __launch_bounds__(256) void k1_gemm_fb(const float* __restrict__ input,
                                                  const unsigned short* __restrict__ w1xt,
                                                  const float* __restrict__ sbp,
                                                  const float* __restrict__ w2,
                                                  float* __restrict__ plog){
  __shared__ unsigned short lds_a[128][72];
  __shared__ unsigned short lds_b[128][72];
  const int orig = blockIdx.x;
  const int xcd  = orig & 7, slot = orig >> 3;
  const int mtile = xcd*64 + (slot >> 2);
  const int nt    = slot & 3;
  const int m0 = mtile * 128, n0 = nt * 128;
  const int b  = m0 >> 11;
  const int t = threadIdx.x;
  const int lane = t & 63, wid = t >> 6;
  const int wr = wid >> 1, wc = wid & 1;
  const int lr = lane & 15, kg = lane >> 4;
  f32x4 acc[4][4];
  #pragma unroll
  for (int mi = 0; mi < 4; ++mi)
    #pragma unroll
    for (int ni = 0; ni < 4; ++ni) acc[mi][ni] = (f32x4){0.f,0.f,0.f,0.f};
  const int ar0 = t >> 4, afo = t & 15;
  const int br0 = t >> 3, bho = t & 7;
  for (int kk = 0; kk < 512; kk += 64){
    #pragma unroll
    for (int rr = 0; rr < 8; ++rr){
      const int r = ar0 + rr*16;
      const float4 v = *reinterpret_cast<const float4*>(input + (size_t)(m0 + r)*512 + kk + afo*4);
      ushort4 bv; bv.x=f2bf(v.x); bv.y=f2bf(v.y); bv.z=f2bf(v.z); bv.w=f2bf(v.w);
      *reinterpret_cast<ushort4*>(&lds_a[r][afo*4]) = bv;
    }
    #pragma unroll
    for (int rr = 0; rr < 4; ++rr){
      const int r = br0 + rr*32;
      const uint4 v = *reinterpret_cast<const uint4*>(w1xt + (size_t)(n0 + r)*512 + kk + bho*8);
      *reinterpret_cast<uint4*>(&lds_b[r][bho*8]) = v;
    }
    __syncthreads();
    #pragma unroll
    for (int ks = 0; ks < 64; ks += 32){
      short8_t af[4], bfr[4];
      #pragma unroll
      for (int mi = 0; mi < 4; ++mi)
        af[mi] = *reinterpret_cast<const short8_t*>(&lds_a[wr*64 + mi*16 + lr][ks + kg*8]);
      #pragma unroll
      for (int ni = 0; ni < 4; ++ni)
        bfr[ni] = *reinterpret_cast<const short8_t*>(&lds_b[wc*64 + ni*16 + lr][ks + kg*8]);
      #pragma unroll
      for (int mi = 0; mi < 4; ++mi)
        #pragma unroll
        for (int ni = 0; ni < 4; ++ni)
          acc[mi][ni] = __builtin_amdgcn_mfma_f32_16x16x32_bf16(af[mi], bfr[ni], acc[mi][ni], 0, 0, 0);
    }
    __syncthreads();
  }
  float w2v[4], sbv[4];
  #pragma unroll
  for (int ni = 0; ni < 4; ++ni){
    const int h = n0 + wc*64 + ni*16 + lr;
    w2v[ni] = w2[h];
    float s = 0.f;
    #pragma unroll
    for (int ds = 0; ds < 8; ++ds) s += sbp[(size_t)(ds*32 + b)*512 + h];
    sbv[ni] = s;
  }
  float* red = reinterpret_cast<float*>(&lds_a[0][0]);
  #pragma unroll
  for (int mi = 0; mi < 4; ++mi){
    #pragma unroll
    for (int j = 0; j < 4; ++j){
      float v = 0.f;
      #pragma unroll
      for (int ni = 0; ni < 4; ++ni)
        v += tanh_cheap(tanh_cheap(acc[mi][ni][j] + sbv[ni])) * w2v[ni];
      v += __shfl_xor(v, 1); v += __shfl_xor(v, 2);
      v += __shfl_xor(v, 4); v += __shfl_xor(v, 8);
      if (lr == 0){
        const int rloc = wr*64 + mi*16 + kg*4 + j;
        red[wc*128 + rloc] = v;
      }
    }
  }
  __syncthreads();
  if (t < 128) plog[(size_t)nt*65536 + m0 + t] = red[t] + red[128 + t];
}

// ---------------------------------------------------------------- K2: softmax stats
__global__ __launch_bounds__(256) void k2_softmax(const float* __restrict__ plog,
                                                  const float* __restrict__ mask,
                                                  float* __restrict__ out_logit,
                                                  float* __restrict__ mz){
  const int b = blockIdx.x, t = threadIdx.x;
  float l[8]; float mx = -3.4e38f;
  #pragma unroll
  for (int i = 0; i < 8; ++i){
    const size_t idx = (size_t)b*2048 + t + i*256;
    float v = plog[idx] + plog[65536 + idx] + plog[2*65536 + idx] + plog[3*65536 + idx];
    v -= NEG_BIG * (1.0f - mask[idx]);
    l[i] = v;
    out_logit[idx] = v;
    mx = fmaxf(mx, v);
  }
  __shared__ float red[8];
  const int wid = t >> 6, lane = t & 63;
  #pragma unroll
  for (int off = 1; off < 64; off <<= 1) mx = fmaxf(mx, __shfl_xor(mx, off));
  if (lane == 0) red[wid] = mx;
  __syncthreads();
  mx = fmaxf(fmaxf(red[0], red[1]), fmaxf(red[2], red[3]));
  float zs = 0.f;
  #pragma unroll
  for (int i = 0; i < 8; ++i) zs += __expf(l[i] - mx);
  #pragma unroll
  for (int off = 1; off < 64; off <<= 1) zs += __shfl_xor(zs, off);
  if (lane == 0) red[4 + wid] = zs;
  __syncthreads();
  if (t == 0){ mz[b*2] = mx; mz[b*2+1] = red[4]+red[5]+red[6]+red[7]; }
}

// ---------------------------------------------------------------- K3 fast: pool from bf16
__global__ __launch_bounds__(256) void k3_pool_bf(const unsigned short* __restrict__ inb,
                                                  const float* __restrict__ logit,
                                                  const float* __restrict__ mz,
                                                  float* __restrict__ pool){
  const int b = blockIdx.x >> 4, sc = blockIdx.x & 15;
  const int t = threadIdx.x;
  __shared__ float p[128];
  const float m = mz[b*2], invZ = 1.0f / mz[b*2+1];
  if (t < 128) p[t] = __expf(logit[(size_t)b*2048 + sc*128 + t] - m) * invZ;
  __syncthreads();
  const int half = t >> 7, cw = t & 127;
  float a0=0.f,a1=0.f,a2=0.f,a3=0.f;
  const unsigned short* base = inb + ((size_t)b*2048 + sc*128 + half)*512 + cw*4;
  #pragma unroll 4
  for (int i = 0; i < 64; ++i){
    const ushort4 v = *reinterpret_cast<const ushort4*>(base + (size_t)i*1024);
    const float pv = p[half + 2*i];
    a0 += pv*bf2f(v.x); a1 += pv*bf2f(v.y); a2 += pv*bf2f(v.z); a3 += pv*bf2f(v.w);
  }
  float4 o = {a0,a1,a2,a3};
  *reinterpret_cast<float4*>(pool + (size_t)blockIdx.x*1024 + half*512 + cw*4) = o;
}

// ---------------------------------------------------------------- K3 fallback: fp32 input
__global__ __launch_bounds__(256) void k3_pool_f32(const float* __restrict__ input,
                                                   const float* __restrict__ logit,
                                                   const float* __restrict__ mz,
                                                   float* __restrict__ pool){
  const int b = blockIdx.x >> 4, sc = blockIdx.x & 15;
  const int t = threadIdx.x;
  __shared__ float p[128];
  const float m = mz[b*2], invZ = 1.0f / mz[b*2+1];
  if (t < 128) p[t] = __expf(logit[(size_t)b*2048 + sc*128 + t] - m) * invZ;
  __syncthreads();
  float a0 = 0.f, a1 = 0.f;
  const float* base = input + ((size_t)b*2048 + sc*128)*512 + 2*t;
  #pragma unroll 4
  for (int i = 0; i < 128; ++i){
    const float2 v = *reinterpret_cast<const float2*>(base + (size_t)i*512);
    a0 += p[i]*v.x; a1 += p[i]*v.y;
  }
  pool[(size_t)blockIdx.x*512 + 2*t]     = a0;
  pool[(size_t)blockIdx.x*512 + 2*t + 1] = a1;
}

// ---------------------------------------------------------------- K4: reduce partials
__global__ __launch_bounds__(256) void k4_reduce(const float* __restrict__ pool,
                                                 float* __restrict__ out_pooled,
                                                 int nchunks){
  const int tg = blockIdx.x*256 + threadIdx.x;  // 0..16383
  const int b = tg >> 9, d = tg & 511;
  float s = 0.f;
  for (int c = 0; c < nchunks; ++c) s += pool[((size_t)b*nchunks + c)*512 + d];
  out_pooled[tg] = s;
}

// ---------------------------------------------------------------- launch
extern "C" void kernel_launch(void* const* d_in, const int* in_sizes, int n_in,
                              void* d_out, int out_size, void* d_ws, size_t ws_size,
                              hipStream_t stream){
  const float* input = (const float*)d_in[0];
  const float* state = (const float*)d_in[1];
  const float* mask  = (const float*)d_in[2];
  const float* W1    = (const float*)d_in[3];
  const float* w2    = (const float*)d_in[4];

  float* out_pooled = (float*)d_out;
  float* out_logit  = (float*)d_out + 16384;

  char* ws = (char*)d_ws;
  const size_t O_INB = 0;                    // 64 MB
  const size_t O_SBP = 67108864;             // 512 KB (8 x 32 x 512 f32)
  const size_t O_W1X = O_SBP + 524288;       // 512 KB
  const size_t O_PLG = O_W1X + 524288;       // 1 MB
  const size_t O_MZ  = O_PLG + 1048576;      // 256 B
  const size_t O_PL  = O_MZ  + 256;          // 2 MB
  const size_t NEED_FAST = O_PL + 2097152;

  if (ws_size >= NEED_FAST){
    unsigned short* inb  = (unsigned short*)(ws + O_INB);
    float*          sbp  = (float*)(ws + O_SBP);
    unsigned short* w1xt = (unsigned short*)(ws + O_W1X);
    float*          plog = (float*)(ws + O_PLG);
    float*          mz   = (float*)(ws + O_MZ);
    float*          pool = (float*)(ws + O_PL);

    k0_all      <<<2368, 256, 0, stream>>>(input, state, W1, inb, sbp, w1xt, 2048);
    k1_gemm_fast<<<2048, 256, 0, stream>>>(inb, w1xt, sbp, w2, plog);
    k2_softmax  <<<32,   256, 0, stream>>>(plog, mask, out_logit, mz);
    k3_pool_bf  <<<512,  256, 0, stream>>>(inb, out_logit, mz, pool);
    k4_reduce   <<<64,   256, 0, stream>>>(pool, out_pooled, 32);
  } else {
    float*          sbp  = (float*)(ws);                                   // 512 KB
    unsigned short* w1xt = (unsigned short*)(ws + 524288);                 // 512 KB
    float*          plog = (float*)(ws + 1048576);                         // 1 MB
    float*          mz   = (float*)(ws + 2097152);                         // 256 B
    float*          pool = (float*)(ws + 2097408);                         // 1 MB

    k0_all    <<<320,  256, 0, stream>>>(nullptr, state, W1, nullptr, sbp, w1xt, 0);
    k1_gemm_fb<<<2048, 256, 0, stream>>>(input, w1xt, sbp, w2, plog);
    k2_softmax<<<32,   256, 0, stream>>>(plog, mask, out_logit, mz);
    k3_pool_f32<<<512, 256, 0, stream>>>(input, out_logit, mz, pool);
    k4_reduce <<<64,   256, 0, stream>>>(pool, out_pooled, 16);
  }
}

// Round 7
// 117.400 us; speedup vs baseline: 1.7232x; 1.0597x over previous
//
#include <hip/hip_runtime.h>
#include <cstdint>
#include <cstddef>

// Problem: B=32, S=2048, D=512, H=512
//   sb[b,h]   = state @ W1[:D]
//   h         = tanh(tanh(sb + input@W1[D:]))   <-- DOUBLE tanh (reference quirk)
//   logit[b,s]= sum_h h * w2[h]  - 1e30*(1-mask)
//   p = softmax over S;  pooled[b,d] = sum_s p*input
// Outputs: pooled (16384 f32) ++ logit (65536 f32)

#define NEG_BIG 1e30f

typedef __attribute__((ext_vector_type(8))) short short8_t;   // 8 x bf16
typedef __attribute__((ext_vector_type(4))) float f32x4;

__device__ inline unsigned short f2bf(float f){
  union { float f; unsigned int u; } v; v.f = f;
  unsigned int r = v.u + 0x7fffu + ((v.u >> 16) & 1u);   // RNE
  return (unsigned short)(r >> 16);
}
__device__ inline float bf2f(unsigned int lo16){
  union { unsigned int u; float f; } v; v.u = lo16 << 16; return v.f;
}
// tanh via 1 - 2/(1+e^{2x}): exp overflow -> inf -> rcp -> 0 -> +1; underflow -> -1.
__device__ inline float tanh_cheap(float x){
  return 1.0f - 2.0f*__builtin_amdgcn_rcpf(1.0f + __expf(2.0f*x));
}

typedef __attribute__((address_space(1))) const unsigned int g_u32;
typedef __attribute__((address_space(3))) unsigned int l_u32;
__device__ inline void gload16(const unsigned short* g, unsigned short* l){
  __builtin_amdgcn_global_load_lds((g_u32*)g, (l_u32*)l, 16, 0, 0);
}

// ---------------------------------------------------------------- K0: merged prologue
// blocks [0, ncvt)           : inb = bf16(input)                (HBM-bound bulk)
// blocks [ncvt, ncvt+64)     : w1xt[h][k] = bf16(W1[512+k][h])  (transpose)
// blocks [ncvt+64, ncvt+320) : sbp[ds][b][h] partial state@W1s  (d-split: 8 slices x 32 b)
__global__ __launch_bounds__(256) void k0_all(const float* __restrict__ input,
                                              const float* __restrict__ state,
                                              const float* __restrict__ W1,
                                              unsigned short* __restrict__ inb,
                                              float* __restrict__ sbp,
                                              unsigned short* __restrict__ w1xt,
                                              int ncvt){
  const int bid = blockIdx.x, t = threadIdx.x;
  if (bid < ncvt) {
    const int tid = bid*256 + t;
    const float4* in4 = (const float4*)input;
    ushort4* o4 = (ushort4*)inb;
    #pragma unroll
    for (int it = 0; it < 16; ++it){
      const size_t i = (size_t)it*524288 + tid;       // 8388608 float4 total
      const float4 v = in4[i];
      ushort4 o; o.x=f2bf(v.x); o.y=f2bf(v.y); o.z=f2bf(v.z); o.w=f2bf(v.w);
      o4[i] = o;
    }
  } else if (bid < ncvt + 64) {
    const int q  = bid - ncvt;
    const int k0 = (q >> 3) * 64, h0 = (q & 7) * 64;
    __shared__ float tile[64][65];
    const int c = t & 63, r0 = t >> 6;
    #pragma unroll
    for (int i = 0; i < 16; ++i){
      int r = r0 + 4*i;
      tile[r][c] = W1[(size_t)(512 + k0 + r)*512 + h0 + c];
    }
    __syncthreads();
    #pragma unroll
    for (int i = 0; i < 16; ++i){
      int r = r0 + 4*i;
      w1xt[(size_t)(h0 + r)*512 + k0 + c] = f2bf(tile[c][r]);
    }
  } else {
    const int idx = bid - ncvt - 64;        // 0..255
    const int b = idx >> 3, ds = idx & 7;
    __shared__ float stl[64];
    if (t < 64) stl[t] = state[b*512 + ds*64 + t];
    __syncthreads();
    float acc0 = 0.f, acc1 = 0.f;
    #pragma unroll 8
    for (int i = 0; i < 64; ++i){
      const float w = stl[i];
      acc0 += w * W1[(size_t)(ds*64 + i)*512 + t];
      acc1 += w * W1[(size_t)(ds*64 + i)*512 + t + 256];
    }
    sbp[(size_t)(ds*32 + b)*512 + t]       = acc0;
    sbp[(size_t)(ds*32 + b)*512 + t + 256] = acc1;
  }
}

// ---------------------------------------------------------------- K1: 256x256 ring-3 counted-vmcnt GEMM
// 512 threads (8 waves 2Mx4N), BK=32, 3 LDS slots (96 KB). Iteration kt:
//   STAGE kt+2 -> slot[(kt+2)%3]   (slot freed by kt-1; issued AFTER the barrier
//                                   that ended all reads of kt-1 -> race-free)
//   ds_read + 32 MFMA on kt from slot[kt%3]
//   s_waitcnt vmcnt(4) (own kt+1 loads landed; kt+2's 4 stay in flight) + s_barrier
// Stage->consume distance = 2 iterations (~500cy) hides L2/L3 latency.
// Read swizzle: chunk16B ^= (row>>1)&3 (2-way banks = free); staged via
// pre-swizzled per-lane GLOBAL source + linear gload_lds dest (rule #21).
__global__ __launch_bounds__(512, 2) void k1_gemm_256(const unsigned short* __restrict__ inb,
                                                      const unsigned short* __restrict__ w1xt,
                                                      const float* __restrict__ sbp,
                                                      const float* __restrict__ w2,
                                                      float* __restrict__ plog){
  __shared__ unsigned short lds[49152];   // A: 3 x 8192 @0, B: 3 x 8192 @24576

  const int orig = blockIdx.x;            // 512 blocks, 512%8==0 -> bijective swizzle
  const int xcd = orig & 7, q = orig >> 3;
  const int mtile = xcd*32 + (q >> 1);    // nt 0/1 of one mtile adjacent on same XCD
  const int nt = q & 1;
  const int m0 = mtile * 256, n0 = nt * 256;
  const int b = m0 >> 11;

  const int t = threadIdx.x;
  const int lane = t & 63, wid = t >> 6;       // 8 waves
  const int wr = wid >> 2, wcn = wid & 3;      // wave -> 128x64 output
  const int lr = lane & 15, kg = lane >> 4;

  // read bases (ushort elems), swizzled k-chunk
  const unsigned swz = (unsigned)((kg ^ ((lr >> 1) & 3)) * 8);
  const unsigned aRd = (unsigned)((wr*128 + lr)*32) + swz;
  const unsigned bRd = 24576u + (unsigned)((wcn*64 + lr)*32) + swz;

  // stage dest (wave-uniform; HW adds lane*16B) + per-lane pre-swizzled global src
  const unsigned aSt = (unsigned)(wid*512);
  const unsigned bSt = 24576u + (unsigned)(wid*512);
  const int srow = wid*16 + (lane >> 2);                  // rows 0..127 (lo half)
  const int sl = ((lane & 3) ^ ((lane >> 3) & 3)) * 8;    // inverse-swizzled chunk
  const unsigned short* gA = inb  + (size_t)(m0 + srow)*512 + sl;
  const unsigned short* gB = w1xt + (size_t)(n0 + srow)*512 + sl;

  unsigned sc = 0, s1 = 8192, s2 = 16384;   // rotating slot offsets (elems)

  f32x4 acc[8][4];
  #pragma unroll
  for (int mi = 0; mi < 8; ++mi)
    #pragma unroll
    for (int ni = 0; ni < 4; ++ni) acc[mi][ni] = (f32x4){0.f,0.f,0.f,0.f};

#define STAGE_KT(kelem, soff) do{ \
    gload16(gA + (kelem),            &lds[aSt + (soff)]); \
    gload16(gA + (kelem) + 65536,    &lds[aSt + 4096 + (soff)]); \
    gload16(gB + (kelem),            &lds[bSt + (soff)]); \
    gload16(gB + (kelem) + 65536,    &lds[bSt + 4096 + (soff)]); }while(0)

  // prologue: kt0 -> slot0, kt1 -> slot1; wait kt0 landed (kt1's 4 in flight)
  STAGE_KT(0, sc);
  STAGE_KT(32, s1);
  asm volatile("s_waitcnt vmcnt(4)\ns_barrier" ::: "memory");

  int kk2 = 64;                              // k-elem offset of kt+2
  for (int kt = 0; kt < 16; ++kt){
    if (kt < 14){ STAGE_KT(kk2, s2); kk2 += 32; }
    short8_t af[8], bf[4];
    #pragma unroll
    for (int mi = 0; mi < 8; ++mi) af[mi] = *(const short8_t*)&lds[aRd + sc + mi*512];
    #pragma unroll
    for (int ni = 0; ni < 4; ++ni) bf[ni] = *(const short8_t*)&lds[bRd + sc + ni*512];
    __builtin_amdgcn_s_setprio(1);
    #pragma unroll
    for (int mi = 0; mi < 8; ++mi)
      #pragma unroll
      for (int ni = 0; ni < 4; ++ni)
        acc[mi][ni] = __builtin_amdgcn_mfma_f32_16x16x32_bf16(af[mi], bf[ni], acc[mi][ni], 0, 0, 0);
    __builtin_amdgcn_s_setprio(0);
    if (kt < 14)       asm volatile("s_waitcnt vmcnt(4)\ns_barrier" ::: "memory");
    else if (kt == 14) asm volatile("s_waitcnt vmcnt(0)\ns_barrier" ::: "memory");
    else               asm volatile("s_barrier" ::: "memory");
    const unsigned tmp = sc; sc = s1; s1 = s2; s2 = tmp;
  }
#undef STAGE_KT

  // epilogue: tanh(tanh(acc + sb)) * w2, reduce over this block's 256 h-cols
  float w2v[4], sbv[4];
  #pragma unroll
  for (int ni = 0; ni < 4; ++ni){
    const int h = n0 + wcn*64 + ni*16 + lr;
    w2v[ni] = w2[h];
    float s = 0.f;
    #pragma unroll
    for (int ds = 0; ds < 8; ++ds) s += sbp[(size_t)(ds*32 + b)*512 + h];
    sbv[ni] = s;
  }
  float* red = reinterpret_cast<float*>(&lds[0]);   // 1024 floats (post-barrier reuse)
  #pragma unroll
  for (int mi = 0; mi < 8; ++mi){
    #pragma unroll
    for (int j = 0; j < 4; ++j){
      float v = 0.f;
      #pragma unroll
      for (int ni = 0; ni < 4; ++ni)
        v += tanh_cheap(tanh_cheap(acc[mi][ni][j] + sbv[ni])) * w2v[ni];
      v += __shfl_xor(v, 1); v += __shfl_xor(v, 2);
      v += __shfl_xor(v, 4); v += __shfl_xor(v, 8);   // sum 16 cols
      if (lr == 0)
        red[wcn*256 + wr*128 + mi*16 + kg*4 + j] = v; // C/D row=(lane>>4)*4+j
    }
  }
  __syncthreads();
  if (t < 256)
    plog[(size_t)nt*65536 + m0 + t] = red[t] + red[256+t] + red[512+t] + red[768+t];
}

// ---------------------------------------------------------------- K1 fallback (reg-staged, pad-72, 4 N-parts)
__global__ __launch_bounds__(256) void k1_gemm_fb(const float* __restrict__ input,
                                                  const unsigned short* __restrict__ w1xt,
                                                  const float* __restrict__ sbp,
                                                  const float* __restrict__ w2,
                                                  float* __restrict__ plog){
  __shared__ unsigned short lds_a[128][72];
  __shared__ unsigned short lds_b[128][72];
  const int orig = blockIdx.x;
  const int xcd  = orig & 7, slot = orig >> 3;
  const int mtile = xcd*64 + (slot >> 2);
  const int nt    = slot & 3;
  const int m0 = mtile * 128, n0 = nt * 128;
  const int b  = m0 >> 11;
  const int t = threadIdx.x;
  const int lane = t & 63, wid = t >> 6;
  const int wr = wid >> 1, wc = wid & 1;
  const int lr = lane & 15, kg = lane >> 4;
  f32x4 acc[4][4];
  #pragma unroll
  for (int mi = 0; mi < 4; ++mi)
    #pragma unroll
    for (int ni = 0; ni < 4; ++ni) acc[mi][ni] = (f32x4){0.f,0.f,0.f,0.f};
  const int ar0 = t >> 4, afo = t & 15;
  const int br0 = t >> 3, bho = t & 7;
  for (int kk = 0; kk < 512; kk += 64){
    #pragma unroll
    for (int rr = 0; rr < 8; ++rr){
      const int r = ar0 + rr*16;
      const float4 v = *reinterpret_cast<const float4*>(input + (size_t)(m0 + r)*512 + kk + afo*4);
      ushort4 bv; bv.x=f2bf(v.x); bv.y=f2bf(v.y); bv.z=f2bf(v.z); bv.w=f2bf(v.w);
      *reinterpret_cast<ushort4*>(&lds_a[r][afo*4]) = bv;
    }
    #pragma unroll
    for (int rr = 0; rr < 4; ++rr){
      const int r = br0 + rr*32;
      const uint4 v = *reinterpret_cast<const uint4*>(w1xt + (size_t)(n0 + r)*512 + kk + bho*8);
      *reinterpret_cast<uint4*>(&lds_b[r][bho*8]) = v;
    }
    __syncthreads();
    #pragma unroll
    for (int ks = 0; ks < 64; ks += 32){
      short8_t af[4], bfr[4];
      #pragma unroll
      for (int mi = 0; mi < 4; ++mi)
        af[mi] = *reinterpret_cast<const short8_t*>(&lds_a[wr*64 + mi*16 + lr][ks + kg*8]);
      #pragma unroll
      for (int ni = 0; ni < 4; ++ni)
        bfr[ni] = *reinterpret_cast<const short8_t*>(&lds_b[wc*64 + ni*16 + lr][ks + kg*8]);
      #pragma unroll
      for (int mi = 0; mi < 4; ++mi)
        #pragma unroll
        for (int ni = 0; ni < 4; ++ni)
          acc[mi][ni] = __builtin_amdgcn_mfma_f32_16x16x32_bf16(af[mi], bfr[ni], acc[mi][ni], 0, 0, 0);
    }
    __syncthreads();
  }
  float w2v[4], sbv[4];
  #pragma unroll
  for (int ni = 0; ni < 4; ++ni){
    const int h = n0 + wc*64 + ni*16 + lr;
    w2v[ni] = w2[h];
    float s = 0.f;
    #pragma unroll
    for (int ds = 0; ds < 8; ++ds) s += sbp[(size_t)(ds*32 + b)*512 + h];
    sbv[ni] = s;
  }
  float* red = reinterpret_cast<float*>(&lds_a[0][0]);
  #pragma unroll
  for (int mi = 0; mi < 4; ++mi){
    #pragma unroll
    for (int j = 0; j < 4; ++j){
      float v = 0.f;
      #pragma unroll
      for (int ni = 0; ni < 4; ++ni)
        v += tanh_cheap(tanh_cheap(acc[mi][ni][j] + sbv[ni])) * w2v[ni];
      v += __shfl_xor(v, 1); v += __shfl_xor(v, 2);
      v += __shfl_xor(v, 4); v += __shfl_xor(v, 8);
      if (lr == 0){
        const int rloc = wr*64 + mi*16 + kg*4 + j;
        red[wc*128 + rloc] = v;
      }
    }
  }
  __syncthreads();
  if (t < 128) plog[(size_t)nt*65536 + m0 + t] = red[t] + red[128 + t];
}

// ---------------------------------------------------------------- K2: softmax stats
__global__ __launch_bounds__(256) void k2_softmax(const float* __restrict__ plog,
                                                  const float* __restrict__ mask,
                                                  float* __restrict__ out_logit,
                                                  float* __restrict__ mz,
                                                  int npart){
  const int b = blockIdx.x, t = threadIdx.x;
  float l[8]; float mx = -3.4e38f;
  #pragma unroll
  for (int i = 0; i < 8; ++i){
    const size_t idx = (size_t)b*2048 + t + i*256;
    float v = 0.f;
    for (int p = 0; p < npart; ++p) v += plog[(size_t)p*65536 + idx];
    v -= NEG_BIG * (1.0f - mask[idx]);
    l[i] = v;
    out_logit[idx] = v;
    mx = fmaxf(mx, v);
  }
  __shared__ float red[8];
  const int wid = t >> 6, lane = t & 63;
  #pragma unroll
  for (int off = 1; off < 64; off <<= 1) mx = fmaxf(mx, __shfl_xor(mx, off));
  if (lane == 0) red[wid] = mx;
  __syncthreads();
  mx = fmaxf(fmaxf(red[0], red[1]), fmaxf(red[2], red[3]));
  float zs = 0.f;
  #pragma unroll
  for (int i = 0; i < 8; ++i) zs += __expf(l[i] - mx);
  #pragma unroll
  for (int off = 1; off < 64; off <<= 1) zs += __shfl_xor(zs, off);
  if (lane == 0) red[4 + wid] = zs;
  __syncthreads();
  if (t == 0){ mz[b*2] = mx; mz[b*2+1] = red[4]+red[5]+red[6]+red[7]; }
}

// ---------------------------------------------------------------- K3 fast: pool from bf16
__global__ __launch_bounds__(256) void k3_pool_bf(const unsigned short* __restrict__ inb,
                                                  const float* __restrict__ logit,
                                                  const float* __restrict__ mz,
                                                  float* __restrict__ pool){
  const int b = blockIdx.x >> 4, sc = blockIdx.x & 15;
  const int t = threadIdx.x;
  __shared__ float p[128];
  const float m = mz[b*2], invZ = 1.0f / mz[b*2+1];
  if (t < 128) p[t] = __expf(logit[(size_t)b*2048 + sc*128 + t] - m) * invZ;
  __syncthreads();
  const int half = t >> 7, cw = t & 127;
  float a0=0.f,a1=0.f,a2=0.f,a3=0.f;
  const unsigned short* base = inb + ((size_t)b*2048 + sc*128 + half)*512 + cw*4;
  #pragma unroll 4
  for (int i = 0; i < 64; ++i){
    const ushort4 v = *reinterpret_cast<const ushort4*>(base + (size_t)i*1024);
    const float pv = p[half + 2*i];
    a0 += pv*bf2f(v.x); a1 += pv*bf2f(v.y); a2 += pv*bf2f(v.z); a3 += pv*bf2f(v.w);
  }
  float4 o = {a0,a1,a2,a3};
  *reinterpret_cast<float4*>(pool + (size_t)blockIdx.x*1024 + half*512 + cw*4) = o;
}

// ---------------------------------------------------------------- K3 fallback: fp32 input
__global__ __launch_bounds__(256) void k3_pool_f32(const float* __restrict__ input,
                                                   const float* __restrict__ logit,
                                                   const float* __restrict__ mz,
                                                   float* __restrict__ pool){
  const int b = blockIdx.x >> 4, sc = blockIdx.x & 15;
  const int t = threadIdx.x;
  __shared__ float p[128];
  const float m = mz[b*2], invZ = 1.0f / mz[b*2+1];
  if (t < 128) p[t] = __expf(logit[(size_t)b*2048 + sc*128 + t] - m) * invZ;
  __syncthreads();
  float a0 = 0.f, a1 = 0.f;
  const float* base = input + ((size_t)b*2048 + sc*128)*512 + 2*t;
  #pragma unroll 4
  for (int i = 0; i < 128; ++i){
    const float2 v = *reinterpret_cast<const float2*>(base + (size_t)i*512);
    a0 += p[i]*v.x; a1 += p[i]*v.y;
  }
  pool[(size_t)blockIdx.x*512 + 2*t]     = a0;
  pool[(size_t)blockIdx.x*512 + 2*t + 1] = a1;
}

// ---------------------------------------------------------------- K4: reduce partials
__global__ __launch_bounds__(256) void k4_reduce(const float* __restrict__ pool,
                                                 float* __restrict__ out_pooled,
                                                 int nchunks){
  const int tg = blockIdx.x*256 + threadIdx.x;  // 0..16383
  const int b = tg >> 9, d = tg & 511;
  float s = 0.f;
  for (int c = 0; c < nchunks; ++c) s += pool[((size_t)b*nchunks + c)*512 + d];
  out_pooled[tg] = s;
}

// ---------------------------------------------------------------- launch
extern "C" void kernel_launch(void* const* d_in, const int* in_sizes, int n_in,
                              void* d_out, int out_size, void* d_ws, size_t ws_size,
                              hipStream_t stream){
  const float* input = (const float*)d_in[0];
  const float* state = (const float*)d_in[1];
  const float* mask  = (const float*)d_in[2];
  const float* W1    = (const float*)d_in[3];
  const float* w2    = (const float*)d_in[4];

  float* out_pooled = (float*)d_out;
  float* out_logit  = (float*)d_out + 16384;

  char* ws = (char*)d_ws;
  const size_t O_INB = 0;                    // 64 MB
  const size_t O_SBP = 67108864;             // 512 KB (8 x 32 x 512 f32)
  const size_t O_W1X = O_SBP + 524288;       // 512 KB
  const size_t O_PLG = O_W1X + 524288;       // 1 MB
  const size_t O_MZ  = O_PLG + 1048576;      // 256 B
  const size_t O_PL  = O_MZ  + 256;          // 2 MB
  const size_t NEED_FAST = O_PL + 2097152;

  if (ws_size >= NEED_FAST){
    unsigned short* inb  = (unsigned short*)(ws + O_INB);
    float*          sbp  = (float*)(ws + O_SBP);
    unsigned short* w1xt = (unsigned short*)(ws + O_W1X);
    float*          plog = (float*)(ws + O_PLG);
    float*          mz   = (float*)(ws + O_MZ);
    float*          pool = (float*)(ws + O_PL);

    k0_all      <<<2368, 256, 0, stream>>>(input, state, W1, inb, sbp, w1xt, 2048);
    k1_gemm_256 <<<512,  512, 0, stream>>>(inb, w1xt, sbp, w2, plog);
    k2_softmax  <<<32,   256, 0, stream>>>(plog, mask, out_logit, mz, 2);
    k3_pool_bf  <<<512,  256, 0, stream>>>(inb, out_logit, mz, pool);
    k4_reduce   <<<64,   256, 0, stream>>>(pool, out_pooled, 32);
  } else {
    float*          sbp  = (float*)(ws);                                   // 512 KB
    unsigned short* w1xt = (unsigned short*)(ws + 524288);                 // 512 KB
    float*          plog = (float*)(ws + 1048576);                         // 1 MB
    float*          mz   = (float*)(ws + 2097152);                         // 256 B
    float*          pool = (float*)(ws + 2097408);                         // 1 MB

    k0_all    <<<320,  256, 0, stream>>>(nullptr, state, W1, nullptr, sbp, w1xt, 0);
    k1_gemm_fb<<<2048, 256, 0, stream>>>(input, w1xt, sbp, w2, plog);
    k2_softmax<<<32,   256, 0, stream>>>(plog, mask, out_logit, mz, 4);
    k3_pool_f32<<<512, 256, 0, stream>>>(input, out_logit, mz, pool);
    k4_reduce <<<64,   256, 0, stream>>>(pool, out_pooled, 16);
  }
}